// Round 10
// baseline (222.649 us; speedup 1.0000x reference)
//
#include <hip/hip_runtime.h>
#include <math.h>

#define B_ 2
#define N_ 2048
#define C_ 256
#define H_ 8
#define HD_ 32
constexpr float LN_EPS_ = 1e-5f;
constexpr float BN_EPS_ = 1e-5f;
constexpr float LOG2E_ = 1.4426950408889634f;
constexpr float ISDL_ = 0.17677669529663687f * 1.4426950408889634f; // 1/sqrt(32)*log2e

typedef __attribute__((ext_vector_type(8))) short bf16x8;
typedef __attribute__((ext_vector_type(4))) float f32x4;

static __device__ inline ushort f2bf(float x) {
    union { float f; uint u; } c{x};
    uint r = (c.u + 0x7FFF + ((c.u >> 16) & 1)) >> 16;
    return (ushort)r;
}
static __device__ inline float bf2f(ushort u) {
    union { uint i; float f; } c; c.i = ((uint)u) << 16; return c.f;
}
static __device__ inline float lane_bcast(float v, int srclane) {
    return __int_as_float(__builtin_amdgcn_ds_bpermute(srclane * 4, __float_as_int(v)));
}
// pack two f32 -> two bf16 (round-half-up): low16 = bf16(lo), high16 = bf16(hi)
static __device__ inline uint pack_bf2(float lo, float hi) {
    uint ul = __float_as_uint(lo) + 0x8000u;
    uint uh = __float_as_uint(hi) + 0x8000u;
    return __builtin_amdgcn_perm(uh, ul, 0x07060302u);
}

// ---------------------------------------------------------------------------
// 0. weight conversion f32 -> bf16. Layout (elements):
//    wq(0) wqd(65536) wk(131072) wkd(196608) wv(262144) wf1(327680) wf2(720896)
// ---------------------------------------------------------------------------
__global__ __launch_bounds__(256)
void k_wconv(const float* __restrict__ Wq, const float* __restrict__ Wqd,
             const float* __restrict__ Wk, const float* __restrict__ Wkd,
             const float* __restrict__ Wv, const float* __restrict__ Wf1,
             const float* __restrict__ Wf2, ushort* __restrict__ dst)
{
    size_t e0 = ((size_t)blockIdx.x * 256 + threadIdx.x) * 8;
    const float* src = Wq; size_t base = 0;
    if (e0 >= 65536)  { src = Wqd; base = 65536; }
    if (e0 >= 131072) { src = Wk;  base = 131072; }
    if (e0 >= 196608) { src = Wkd; base = 196608; }
    if (e0 >= 262144) { src = Wv;  base = 262144; }
    if (e0 >= 327680) { src = Wf1; base = 327680; }
    if (e0 >= 720896) { src = Wf2; base = 720896; }
    float4 a = *(const float4*)(src + (e0 - base));
    float4 b = *(const float4*)(src + (e0 - base) + 4);
    ushort o[8] = {f2bf(a.x), f2bf(a.y), f2bf(a.z), f2bf(a.w),
                   f2bf(b.x), f2bf(b.y), f2bf(b.z), f2bf(b.w)};
    *(uint4*)(dst + e0) = *(uint4*)o;
}

// 0b. bias concat for fused projections
__global__ __launch_bounds__(512)
void k_bconcat(const float* __restrict__ bq, const float* __restrict__ bqd,
               const float* __restrict__ bk, const float* __restrict__ bkd,
               float* __restrict__ bqqd, float* __restrict__ bkkd)
{
    int t = threadIdx.x;
    bqqd[t] = (t < 256) ? bq[t] : bqd[t - 256];
    bkkd[t] = (t < 256) ? bk[t] : bkd[t - 256];
}

// ---------------------------------------------------------------------------
// 1. LN-over-C with transpose: in [B,C,N] f32 -> bf16 rows [(b*N+n)*ld + c]
// ---------------------------------------------------------------------------
template<bool DO_LN>
__global__ __launch_bounds__(256)
void k_ln_transpose(const float* __restrict__ x,
                    const float* __restrict__ g,
                    const float* __restrict__ bt,
                    ushort* __restrict__ out, int ld)
{
    __shared__ float tile[C_][65];
    __shared__ float red_s[4][64];
    __shared__ float red_q[4][64];
    __shared__ float ms[64];
    __shared__ float rs[64];

    const int b  = blockIdx.x / (N_ / 64);
    const int n0 = (blockIdx.x % (N_ / 64)) * 64;
    const int tid = threadIdx.x;

    for (int i = 0; i < 64; ++i) {
        int c = i * 4 + (tid >> 6);
        int n = tid & 63;
        tile[c][n] = x[((size_t)b * C_ + c) * N_ + n0 + n];
    }
    __syncthreads();

    float gv = 0.f, bv = 0.f;
    if (DO_LN) { gv = g[tid]; bv = bt[tid]; }

    if (DO_LN) {
        const int nl = tid & 63, part = tid >> 6;
        float s = 0.f, q = 0.f;
        for (int j = 0; j < 64; ++j) {
            float v = tile[part * 64 + j][nl];
            s += v; q += v * v;
        }
        red_s[part][nl] = s; red_q[part][nl] = q;
        __syncthreads();
        if (tid < 64) {
            float ss = red_s[0][tid] + red_s[1][tid] + red_s[2][tid] + red_s[3][tid];
            float qq = red_q[0][tid] + red_q[1][tid] + red_q[2][tid] + red_q[3][tid];
            float mean = ss * (1.0f / C_);
            float var  = qq * (1.0f / C_) - mean * mean;
            ms[tid] = mean;
            rs[tid] = rsqrtf(var + LN_EPS_);
        }
        __syncthreads();
    }

    for (int i = 0; i < 64; ++i) {
        float v = tile[tid][i];
        if (DO_LN) v = (v - ms[i]) * rs[i] * gv + bv;
        out[((size_t)b * N_ + n0 + i) * ld + tid] = f2bf(v);
    }
}

// ---------------------------------------------------------------------------
// 2a. MFMA NT GEMM, 64x64 tile (kept for small-grid shapes: v^T, Wf2)
// ---------------------------------------------------------------------------
template<int EPI, int OUT>
__global__ __launch_bounds__(256)
void k_gemm_bf(const ushort* __restrict__ A, int lda, size_t sAz,
               const ushort* __restrict__ Bw, int ldb, size_t sBz,
               void* __restrict__ Cout_, int ldc, size_t sCz,
               int K,
               const float* __restrict__ aux1,
               const float* __restrict__ aux2)
{
    const int z = blockIdx.z;
    A  += (size_t)z * sAz;
    Bw += (size_t)z * sBz;

    const int r0 = blockIdx.x * 64;
    const int c0 = blockIdx.y * 64;
    const int tid = threadIdx.x;
    const int w = tid >> 6, lane = tid & 63;
    const int wr = w >> 1, wc = w & 1;
    const int ql = lane & 15, g = lane >> 4;

    __shared__ ushort As[64][40];
    __shared__ ushort Bs[64][40];

    f32x4 acc[2][2] = {};
    const int srow = tid >> 2;
    const int sk   = (tid & 3) * 8;

    for (int k0 = 0; k0 < K; k0 += 32) {
        bf16x8 av = *(const bf16x8*)&A[(size_t)(r0 + srow) * lda + k0 + sk];
        bf16x8 bv = *(const bf16x8*)&Bw[(size_t)(c0 + srow) * ldb + k0 + sk];
        __syncthreads();
        *(bf16x8*)&As[srow][sk] = av;
        *(bf16x8*)&Bs[srow][sk] = bv;
        __syncthreads();
        bf16x8 af[2], bf[2];
        #pragma unroll
        for (int i = 0; i < 2; ++i) {
            af[i] = *(const bf16x8*)&As[wr * 32 + i * 16 + ql][8 * g];
            bf[i] = *(const bf16x8*)&Bs[wc * 32 + i * 16 + ql][8 * g];
        }
        #pragma unroll
        for (int mi = 0; mi < 2; ++mi)
            #pragma unroll
            for (int ni = 0; ni < 2; ++ni)
                acc[mi][ni] = __builtin_amdgcn_mfma_f32_16x16x32_bf16(af[mi], bf[ni], acc[mi][ni], 0, 0, 0);
    }

    const float inv_bn = rsqrtf(1.0f + BN_EPS_);
    float*  Cf = (float*)Cout_  + (size_t)z * sCz;
    ushort* Cb = (ushort*)Cout_ + (size_t)z * sCz;
    #pragma unroll
    for (int mi = 0; mi < 2; ++mi) {
        #pragma unroll
        for (int ni = 0; ni < 2; ++ni) {
            #pragma unroll
            for (int r = 0; r < 4; ++r) {
                int row = r0 + wr * 32 + mi * 16 + 4 * g + r;
                int col = c0 + wc * 32 + ni * 16 + ql;
                float v = acc[mi][ni][r];
                if (EPI == 0) {
                    v += aux1[col];
                } else if (EPI == 1) {
                    float qnv = aux1[(size_t)z * N_ + row];
                    float knv = aux2[(size_t)z * N_ + col];
                    v = sqrtf(fmaxf(qnv + knv - 2.0f * v, 0.f));
                } else if (EPI == 2) {
                    v = fmaxf(v * (aux1[col] * inv_bn) + aux2[col], 0.f);
                } else if (EPI == 3) {
                    v += aux1[row];
                }
                if (OUT == 0) Cf[(size_t)row * ldc + col] = v;
                else          Cb[(size_t)row * ldc + col] = f2bf(v);
            }
        }
    }
}

// ---------------------------------------------------------------------------
// 2b. MFMA NT GEMM, 128x128 tile (m93-structure): 4 waves (2x2 quadrants),
//     4x4 fragments/wave, BK=32, reg-staged, padded LDS rows (72B) so the
//     16-lane fragment read maps ql -> bank-group 18*ql mod 32 (a permutation
//     -> conflict-free). 16 MFMA per wave per K-step.
// ---------------------------------------------------------------------------
template<int EPI, int OUT>
__global__ __launch_bounds__(256)
void k_gemm128(const ushort* __restrict__ A, int lda, size_t sAz,
               const ushort* __restrict__ Bw, int ldb, size_t sBz,
               void* __restrict__ Cout_, int ldc, size_t sCz,
               int K,
               const float* __restrict__ aux1,
               const float* __restrict__ aux2)
{
    const int z = blockIdx.z;
    A  += (size_t)z * sAz;
    Bw += (size_t)z * sBz;

    const int r0 = blockIdx.x * 128;
    const int c0 = blockIdx.y * 128;
    const int tid = threadIdx.x;
    const int w = tid >> 6, lane = tid & 63;
    const int wr = w >> 1, wc = w & 1;
    const int ql = lane & 15, g = lane >> 4;

    __shared__ ushort As[128][36];
    __shared__ ushort Bs[128][36];

    f32x4 acc[4][4] = {};
    const int srow = tid >> 2;          // 0..63
    const int sk   = (tid & 3) * 8;

    for (int k0 = 0; k0 < K; k0 += 32) {
        bf16x8 a0 = *(const bf16x8*)&A[(size_t)(r0 + srow) * lda + k0 + sk];
        bf16x8 a1 = *(const bf16x8*)&A[(size_t)(r0 + 64 + srow) * lda + k0 + sk];
        bf16x8 b0 = *(const bf16x8*)&Bw[(size_t)(c0 + srow) * ldb + k0 + sk];
        bf16x8 b1 = *(const bf16x8*)&Bw[(size_t)(c0 + 64 + srow) * ldb + k0 + sk];
        __syncthreads();                 // prior frag reads done
        *(bf16x8*)&As[srow][sk]      = a0;
        *(bf16x8*)&As[64 + srow][sk] = a1;
        *(bf16x8*)&Bs[srow][sk]      = b0;
        *(bf16x8*)&Bs[64 + srow][sk] = b1;
        __syncthreads();
        bf16x8 af[4], bf[4];
        #pragma unroll
        for (int i = 0; i < 4; ++i) {
            af[i] = *(const bf16x8*)&As[wr * 64 + i * 16 + ql][8 * g];
            bf[i] = *(const bf16x8*)&Bs[wc * 64 + i * 16 + ql][8 * g];
        }
        #pragma unroll
        for (int mi = 0; mi < 4; ++mi)
            #pragma unroll
            for (int ni = 0; ni < 4; ++ni)
                acc[mi][ni] = __builtin_amdgcn_mfma_f32_16x16x32_bf16(af[mi], bf[ni], acc[mi][ni], 0, 0, 0);
    }

    const float inv_bn = rsqrtf(1.0f + BN_EPS_);
    float*  Cf = (float*)Cout_  + (size_t)z * sCz;
    ushort* Cb = (ushort*)Cout_ + (size_t)z * sCz;
    #pragma unroll
    for (int mi = 0; mi < 4; ++mi) {
        #pragma unroll
        for (int ni = 0; ni < 4; ++ni) {
            #pragma unroll
            for (int r = 0; r < 4; ++r) {
                int row = r0 + wr * 64 + mi * 16 + 4 * g + r;
                int col = c0 + wc * 64 + ni * 16 + ql;
                float v = acc[mi][ni][r];
                if (EPI == 0) {
                    v += aux1[col];
                } else if (EPI == 1) {
                    float qnv = aux1[(size_t)z * N_ + row];
                    float knv = aux2[(size_t)z * N_ + col];
                    v = sqrtf(fmaxf(qnv + knv - 2.0f * v, 0.f));
                } else if (EPI == 2) {
                    v = fmaxf(v * (aux1[col] * inv_bn) + aux2[col], 0.f);
                } else if (EPI == 3) {
                    v += aux1[row];
                }
                if (OUT == 0) Cf[(size_t)row * ldc + col] = v;
                else          Cb[(size_t)row * ldc + col] = f2bf(v);
            }
        }
    }
}

// ---------------------------------------------------------------------------
// 3. row squared-norm over bf16 rows [R,256] with row stride ld
// ---------------------------------------------------------------------------
__global__ __launch_bounds__(256)
void k_rownorm(const ushort* __restrict__ x, int ld, float* __restrict__ outn)
{
    const int r = blockIdx.x * 4 + (threadIdx.x >> 6);
    const int lane = threadIdx.x & 63;
    uint2 pv = *(const uint2*)&x[(size_t)r * ld + lane * 4];
    float v0 = bf2f((ushort)(pv.x & 0xffff)), v1 = bf2f((ushort)(pv.x >> 16));
    float v2 = bf2f((ushort)(pv.y & 0xffff)), v3 = bf2f((ushort)(pv.y >> 16));
    float s = v0 * v0 + v1 * v1 + v2 * v2 + v3 * v3;
    #pragma unroll
    for (int off = 32; off; off >>= 1) s += __shfl_xor(s, off);
    if (lane == 0) outn[r] = s;
}

// ---------------------------------------------------------------------------
// 4. fused attention v5: split-m + split-head. 512 thr = 8 waves =
//    (2 paths x 4 heads). grid (N/16, B, 2 half x 2 head-group).
// ---------------------------------------------------------------------------
#define QLD_ 512
__global__ __launch_bounds__(512, 4)
void k_attn5(const ushort* __restrict__ q_bf,  // [B*N][512] (cols 0..255 = q)
             const ushort* __restrict__ k_bf,  // [B*N][512] (cols 0..255 = k)
             const ushort* __restrict__ v_c,   // [B][256][N]
             const float* __restrict__ xyzA,   // [B][N][3]
             const float* __restrict__ xyzB,   // [B][N][3]
             const ushort* __restrict__ cdb,   // [B][N][N] bf16
             const float* __restrict__ sb_w1, const float* __restrict__ sb_bn_g,
             const float* __restrict__ sb_bn_b, const float* __restrict__ sb_w2,
             const float* __restrict__ sb_b2,
             ushort* __restrict__ pc,          // [half*2+path][B*N][256] bf16
             float* __restrict__ pml)          // [half*2+path][B*N][H][2]
{
    __shared__ ushort biasL[4][16][72];   // [local h][q][m] bf16 (log2e domain)
    __shared__ float  cds[16][68];        // [q][m] cd*log2e
    __shared__ ushort ps[8][16][72];      // per-wave P (bf16)
    __shared__ float  w2Ls[4][4];         // local head weights (log2e-scaled)
    __shared__ float  b2Ls[4];

    const int n0 = blockIdx.x * 16;
    const int b  = blockIdx.y;
    const int hg   = blockIdx.z & 1;      // head group: heads hg*4 .. hg*4+3
    const int half = blockIdx.z >> 1;     // m-range half
    const size_t bN = (size_t)b * N_;
    const int tid = threadIdx.x;
    const int w = tid >> 6, lane = tid & 63;
    const int path = w >> 2, hl = w & 3;
    const int h = hg * 4 + hl;
    const int ql = lane & 15, g = lane >> 4;

    if (tid < 4) {
        b2Ls[tid] = sb_b2[hg * 4 + tid] * LOG2E_;
        #pragma unroll
        for (int i = 0; i < 4; ++i) w2Ls[tid][i] = sb_w2[(hg * 4 + tid) * 4 + i] * LOG2E_;
    }

    const float inv_bn = rsqrtf(1.0f + BN_EPS_);
    float w1s_[4], bnb_[4];
    #pragma unroll
    for (int i = 0; i < 4; ++i) {
        w1s_[i] = sb_w1[i] * sb_bn_g[i] * inv_bn;
        bnb_[i] = sb_bn_b[i];
    }

    // coop indices: 512 threads = 16 q x 32 m-pairs
    const int cq = tid >> 5, cm2 = tid & 31;
    const float ax = xyzA[(bN + n0 + cq) * 3 + 0];
    const float ay = xyzA[(bN + n0 + cq) * 3 + 1];
    const float az = xyzA[(bN + n0 + cq) * 3 + 2];

    bf16x8 qfrag = {};
    if (path == 0)
        qfrag = *(const bf16x8*)&q_bf[(bN + n0 + ql) * QLD_ + h * 32 + 8 * g];

    float m_i = -INFINITY, l_i = 0.f;
    f32x4 ctx0 = {0.f, 0.f, 0.f, 0.f};
    f32x4 ctx1 = {0.f, 0.f, 0.f, 0.f};
    const f32x4 zf = {0.f, 0.f, 0.f, 0.f};

    const int tBeg = half * (N_ / 128);          // 16 tiles per half
    const int tEnd = tBeg + (N_ / 128);

    for (int t = tBeg; t < tEnd; ++t) {
        const int m0 = t * 64;
        __syncthreads();   // prior tile's LDS reads done (also covers w2Ls init)

        // ---- coop: bias[4][16][64] bf16 + cds ----
        {
            const int mA = m0 + 2 * cm2;
            const float* pb = xyzB + (bN + mA) * 3;
            float bx0 = pb[0], by0 = pb[1], bz0 = pb[2];
            float bx1 = pb[3], by1 = pb[4], bz1 = pb[5];
            float dx0 = ax - bx0, dy0 = ay - by0, dz0 = az - bz0;
            float dx1 = ax - bx1, dy1 = ay - by1, dz1 = az - bz1;
            float d0 = sqrtf(dx0 * dx0 + dy0 * dy0 + dz0 * dz0);
            float d1 = sqrtf(dx1 * dx1 + dy1 * dy1 + dz1 * dz1);
            float f0[4], f1[4];
            #pragma unroll
            for (int i = 0; i < 4; ++i) {
                f0[i] = fmaxf(fmaf(-w1s_[i], d0, bnb_[i]), 0.f);
                f1[i] = fmaxf(fmaf(-w1s_[i], d1, bnb_[i]), 0.f);
            }
            #pragma unroll
            for (int hh = 0; hh < 4; ++hh) {
                const f32x4 w2v = *(const f32x4*)w2Ls[hh];
                float b0 = b2Ls[hh], b1 = b2Ls[hh];
                #pragma unroll
                for (int i = 0; i < 4; ++i) {
                    b0 = fmaf(w2v[i], f0[i], b0);
                    b1 = fmaf(w2v[i], f1[i], b1);
                }
                *(uint*)&biasL[hh][cq][2 * cm2] = pack_bf2(b0, b1);
            }
            uint cv = *(const uint*)&cdb[(bN + n0 + cq) * (size_t)N_ + mA];
            cds[cq][2 * cm2]     = bf2f((ushort)(cv & 0xffff)) * LOG2E_;
            cds[cq][2 * cm2 + 1] = bf2f((ushort)(cv >> 16)) * LOG2E_;
        }
        __syncthreads();

        // ---- per-wave: issue global loads early ----
        bf16x8 af[4];
        if (path == 0) {
            #pragma unroll
            for (int mt = 0; mt < 4; ++mt)
                af[mt] = *(const bf16x8*)&k_bf[(bN + m0 + mt * 16 + ql) * QLD_ + h * 32 + 8 * g];
        }
        bf16x8 vb[2][2];
        #pragma unroll
        for (int kb = 0; kb < 2; ++kb)
            #pragma unroll
            for (int dt = 0; dt < 2; ++dt)
                vb[kb][dt] = *(const bf16x8*)&v_c[((size_t)b * C_ + h * 32 + dt * 16 + ql) * N_ + m0 + kb * 32 + 8 * g];

        // ---- s init from bias LDS ----
        float s[16];
        #pragma unroll
        for (int mt = 0; mt < 4; ++mt) {
            uint2 bw = *(const uint2*)&biasL[hl][ql][16 * mt + 4 * g];
            s[4 * mt + 0] = __uint_as_float(bw.x << 16);
            s[4 * mt + 1] = __uint_as_float(bw.x & 0xffff0000u);
            s[4 * mt + 2] = __uint_as_float(bw.y << 16);
            s[4 * mt + 3] = __uint_as_float(bw.y & 0xffff0000u);
        }

        if (path == 0) {
            #pragma unroll
            for (int mt = 0; mt < 4; ++mt) {
                f32x4 sf = __builtin_amdgcn_mfma_f32_16x16x32_bf16(af[mt], qfrag, zf, 0, 0, 0);
                #pragma unroll
                for (int r = 0; r < 4; ++r)
                    s[4 * mt + r] = fmaf(sf[r], ISDL_, s[4 * mt + r]);
            }
        } else {
            #pragma unroll
            for (int mt = 0; mt < 4; ++mt) {
                f32x4 cv = *(const f32x4*)&cds[ql][16 * mt + 4 * g];
                #pragma unroll
                for (int r = 0; r < 4; ++r)
                    s[4 * mt + r] += cv[r];
            }
        }

        // ---- online softmax with defer-max ----
        float tmax = s[0];
        #pragma unroll
        for (int j = 1; j < 16; ++j) tmax = fmaxf(tmax, s[j]);
        tmax = fmaxf(tmax, __shfl_xor(tmax, 16));
        tmax = fmaxf(tmax, __shfl_xor(tmax, 32));
        if (!__all(tmax <= m_i + 8.0f)) {
            float mnew = fmaxf(m_i, tmax);
            float scl = exp2f(m_i - mnew);
            l_i *= scl;
            #pragma unroll
            for (int r = 0; r < 4; ++r) {
                float sr = lane_bcast(scl, 4 * g + r);
                ctx0[r] *= sr; ctx1[r] *= sr;
            }
            m_i = mnew;
        }
        float lsum = 0.f;
        #pragma unroll
        for (int j = 0; j < 16; ++j) {
            float pj = exp2f(s[j] - m_i);
            s[j] = pj;
            lsum += pj;
        }
        lsum += __shfl_xor(lsum, 16);
        lsum += __shfl_xor(lsum, 32);
        l_i += lsum;

        // ---- pack P -> per-wave LDS ----
        #pragma unroll
        for (int mt = 0; mt < 4; ++mt) {
            uint2 pk;
            pk.x = pack_bf2(s[4 * mt + 0], s[4 * mt + 1]);
            pk.y = pack_bf2(s[4 * mt + 2], s[4 * mt + 3]);
            *(uint2*)&ps[w][ql][16 * mt + 4 * g] = pk;
        }

        // ---- PV ----
        #pragma unroll
        for (int kb = 0; kb < 2; ++kb) {
            bf16x8 pa = *(const bf16x8*)&ps[w][ql][kb * 32 + 8 * g];
            ctx0 = __builtin_amdgcn_mfma_f32_16x16x32_bf16(pa, vb[kb][0], ctx0, 0, 0, 0);
            ctx1 = __builtin_amdgcn_mfma_f32_16x16x32_bf16(pa, vb[kb][1], ctx1, 0, 0, 0);
        }
    }

    // ---- epilogue: unnormalized partial ctx (bf16) + (m,l) ----
    const size_t sl = (size_t)(half * 2 + path) * (B_ * N_);
    #pragma unroll
    for (int r = 0; r < 4; ++r) {
        size_t base = (sl + bN + n0 + 4 * g + r) * C_ + h * 32;
        pc[base + ql]      = f2bf(ctx0[r]);
        pc[base + 16 + ql] = f2bf(ctx1[r]);
    }
    if (g == 0) {
        size_t mlb = ((sl + bN + n0 + ql) * H_ + h) * 2;
        pml[mlb]     = m_i;
        pml[mlb + 1] = l_i;
    }
}

// ---------------------------------------------------------------------------
// 5. merge halves + LayerNorm, write bf16 into fused_bf columns.
// ---------------------------------------------------------------------------
__global__ __launch_bounds__(256)
void k_merge_ln(const ushort* __restrict__ pc, const float* __restrict__ pml,
                const float* __restrict__ g_sim, const float* __restrict__ b_sim,
                const float* __restrict__ g_dis, const float* __restrict__ b_dis,
                ushort* __restrict__ fused_bf)
{
    __shared__ float rs_[4], rq_[4];
    const int row = blockIdx.x;           // global row in [0, B*N)
    const int path = blockIdx.y;
    const int c = threadIdx.x;
    const int h = c >> 5;
    const size_t i0 = (size_t)(0 * 2 + path) * (B_ * N_) + row;
    const size_t i1 = (size_t)(1 * 2 + path) * (B_ * N_) + row;
    const float m0 = pml[(i0 * H_ + h) * 2], l0 = pml[(i0 * H_ + h) * 2 + 1];
    const float m1 = pml[(i1 * H_ + h) * 2], l1 = pml[(i1 * H_ + h) * 2 + 1];
    const float M = fmaxf(m0, m1);
    const float w0 = exp2f(m0 - M), w1 = exp2f(m1 - M);
    const float il = 1.0f / fmaf(l0, w0, l1 * w1);
    const float v = fmaf(bf2f(pc[i0 * C_ + c]), w0, bf2f(pc[i1 * C_ + c]) * w1) * il;

    float s = v, q = v * v;
    #pragma unroll
    for (int off = 32; off; off >>= 1) { s += __shfl_xor(s, off); q += __shfl_xor(q, off); }
    const int wv = c >> 6, lane = c & 63;
    if (lane == 0) { rs_[wv] = s; rq_[wv] = q; }
    __syncthreads();
    float ss = rs_[0] + rs_[1] + rs_[2] + rs_[3];
    float qq = rq_[0] + rq_[1] + rq_[2] + rq_[3];
    float mean = ss * (1.0f / C_);
    float var  = qq * (1.0f / C_) - mean * mean;
    float rstd = rsqrtf(var + LN_EPS_);
    const float* gp = path ? g_dis : g_sim;
    const float* bp = path ? b_dis : b_sim;
    fused_bf[(size_t)row * (3 * C_) + C_ + path * C_ + c] =
        f2bf((v - mean) * rstd * gp[c] + bp[c]);
}

// ---------------------------------------------------------------------------
// 6. transpose [B*N,256] f32 -> [B,C,N] and add residual featA
// ---------------------------------------------------------------------------
__global__ __launch_bounds__(256)
void k_transpose_add(const float* __restrict__ fused_t,
                     const float* __restrict__ featA,
                     float* __restrict__ out)
{
    __shared__ float t[64][65];
    const int n0 = blockIdx.x * 64, c0 = blockIdx.y * 64, b = blockIdx.z;
    const int tid = threadIdx.x;
    #pragma unroll
    for (int i = 0; i < 16; ++i) {
        int e = i * 256 + tid;
        int nn = e >> 6, cc = e & 63;
        t[nn][cc] = fused_t[((size_t)b * N_ + n0 + nn) * C_ + c0 + cc];
    }
    __syncthreads();
    #pragma unroll
    for (int i = 0; i < 16; ++i) {
        int e = i * 256 + tid;
        int cc = e >> 6, nn = e & 63;
        size_t idx = ((size_t)b * C_ + c0 + cc) * N_ + n0 + nn;
        out[idx] = t[nn][cc] + featA[idx];
    }
}

// ---------------------------------------------------------------------------
extern "C" void kernel_launch(void* const* d_in, const int* in_sizes, int n_in,
                              void* d_out, int out_size, void* d_ws, size_t ws_size,
                              hipStream_t stream)
{
    const float* xyz_A   = (const float*)d_in[0];
    const float* featA   = (const float*)d_in[1];
    const float* xyz_B   = (const float*)d_in[2];
    const float* featB   = (const float*)d_in[3];
    const float* ln_in_g = (const float*)d_in[4];
    const float* ln_in_b = (const float*)d_in[5];
    const float* Wq  = (const float*)d_in[6];
    const float* bq  = (const float*)d_in[7];
    const float* Wk  = (const float*)d_in[8];
    const float* bk  = (const float*)d_in[9];
    const float* Wv  = (const float*)d_in[10];
    const float* bv  = (const float*)d_in[11];
    const float* sb_w1   = (const float*)d_in[12];
    const float* sb_bn_g = (const float*)d_in[13];
    const float* sb_bn_b = (const float*)d_in[14];
    const float* sb_w2   = (const float*)d_in[15];
    const float* sb_b2   = (const float*)d_in[16];
    const float* Wqd = (const float*)d_in[17];
    const float* bqd = (const float*)d_in[18];
    const float* Wkd = (const float*)d_in[19];
    const float* bkd = (const float*)d_in[20];
    const float* ln_sim_g = (const float*)d_in[21];
    const float* ln_sim_b = (const float*)d_in[22];
    const float* ln_dis_g = (const float*)d_in[23];
    const float* ln_dis_b = (const float*)d_in[24];
    const float* Wf1   = (const float*)d_in[25];
    const float* bnf_g = (const float*)d_in[26];
    const float* bnf_b = (const float*)d_in[27];
    const float* Wf2   = (const float*)d_in[28];
    const float* bf2   = (const float*)d_in[29];
    float* out = (float*)d_out;

    float* ws = (float*)d_ws;
    size_t off = 0;
    auto alloc = [&](size_t n) { float* p = ws + off; off += n; return p; };
    const size_t RN = (size_t)B_ * N_;   // 4096 rows

    ushort* fused_bf = (ushort*)alloc(RN * 384);       // [RN][768] bf16
    ushort* featB_bf = (ushort*)alloc(RN * 128);       // [RN][256] bf16
    ushort* qqd_bf   = (ushort*)alloc(RN * 256);       // [RN][512] bf16 (q|qd)
    ushort* kkd_bf   = (ushort*)alloc(RN * 256);       // [RN][512] bf16 (k|kd)
    ushort* v_bf     = (ushort*)alloc(RN * 128);       // [B][256][N] bf16
    ushort* wbf      = (ushort*)alloc(425984);         // 851968 bf16 weights
    float*  bqqd     = alloc(512);
    float*  bkkd     = alloc(512);
    float*  qn       = alloc(RN);
    float*  kn       = alloc(RN);
    ushort* cd_bf    = (ushort*)alloc((size_t)B_ * N_ * N_ / 2); // bf16; reused fh+fused_t
    ushort* pc       = (ushort*)alloc(4 * RN * C_ / 2);// [4][RN][256] bf16 partial ctx
    float*  pml      = alloc(4 * RN * H_ * 2);         // [4][RN][H][2]

    ushort* q_bf  = qqd_bf;            // stride 512, cols 0..255
    ushort* qd_bf = qqd_bf + 256;      // stride 512
    ushort* k_bf  = kkd_bf;
    ushort* kd_bf = kkd_bf + 256;
    ushort* fh      = cd_bf;                            // [RN][512] bf16 (cd dead after attn)
    float*  fused_t = (float*)(cd_bf + (size_t)RN * 512); // f32 [RN][256]

    ushort* wqqd_bf = wbf;             // [512][256]
    ushort* wkkd_bf = wbf + 131072;    // [512][256]
    ushort* wv_bf   = wbf + 262144;
    ushort* wf1_bf  = wbf + 327680;
    ushort* wf2_bf  = wbf + 720896;
    (void)ws_size; (void)in_sizes; (void)n_in; (void)out_size;

    dim3 blk(256);

    // 0) weights -> bf16 ; biases concat ; 1) LN/transpose -> bf16
    k_wconv<<<dim3(416), blk, 0, stream>>>(Wq, Wqd, Wk, Wkd, Wv, Wf1, Wf2, wbf);
    k_bconcat<<<dim3(1), dim3(512), 0, stream>>>(bq, bqd, bk, bkd, bqqd, bkkd);
    k_ln_transpose<true ><<<dim3(B_ * (N_ / 64)), blk, 0, stream>>>(featA, ln_in_g, ln_in_b, fused_bf, 3 * C_);
    k_ln_transpose<false><<<dim3(B_ * (N_ / 64)), blk, 0, stream>>>(featB, nullptr, nullptr, featB_bf, C_);

    // 2) fused projections: q|qd, k|kd on 128^2; v^T on 64^2 (small grid)
    k_gemm128<0,1><<<dim3(RN / 128, 4, 1), blk, 0, stream>>>(fused_bf, 3 * C_, 0, wqqd_bf, C_, 0, qqd_bf, 512, 0, C_, bqqd, nullptr);
    k_gemm128<0,1><<<dim3(RN / 128, 4, 1), blk, 0, stream>>>(featB_bf, C_,     0, wkkd_bf, C_, 0, kkd_bf, 512, 0, C_, bkkd, nullptr);
    k_gemm_bf<3,1><<<dim3(C_ / 64, N_ / 64, B_), blk, 0, stream>>>(wv_bf, C_, 0, featB_bf, C_, (size_t)N_ * C_, v_bf, N_, (size_t)C_ * N_, C_, bv, nullptr);

    // 3) feature-cdist (bf16 out, 128^2 tile)
    k_rownorm<<<dim3(RN / 4), blk, 0, stream>>>(qd_bf, 512, qn);
    k_rownorm<<<dim3(RN / 4), blk, 0, stream>>>(kd_bf, 512, kn);
    k_gemm128<1,1><<<dim3(N_ / 128, N_ / 128, B_), blk, 0, stream>>>(qd_bf, 512, (size_t)N_ * 512,
                                                                     kd_bf, 512, (size_t)N_ * 512,
                                                                     cd_bf, N_, (size_t)N_ * N_, C_, qn, kn);

    // 4) fused attention v5 (split-m + split-head) + fused merge+LN
    k_attn5<<<dim3(N_ / 16, B_, 4), dim3(512), 0, stream>>>(q_bf, k_bf, v_bf, xyz_A, xyz_B, cd_bf,
                                                            sb_w1, sb_bn_g, sb_bn_b, sb_w2, sb_b2,
                                                            pc, pml);
    k_merge_ln<<<dim3(RN, 2), blk, 0, stream>>>(pc, pml, ln_sim_g, ln_sim_b, ln_dis_g, ln_dis_b, fused_bf);

    // 5) fused MLP: Wf1 on 128^2, Wf2 on 64^2 (N=256 -> 128^2 grid too small)
    k_gemm128<2,1><<<dim3(RN / 128, 4, 1), blk, 0, stream>>>(fused_bf, 3 * C_, 0, wf1_bf, 3 * C_, 0, fh, 2 * C_, 0, 3 * C_, bnf_g, bnf_b);
    k_gemm_bf<0,0><<<dim3(RN / 64, C_ / 64, 1), blk, 0, stream>>>(fh, 2 * C_, 0, wf2_bf, 2 * C_, 0, fused_t, C_, 0, 2 * C_, bf2, nullptr);

    // 6) transpose + residual
    k_transpose_add<<<dim3(N_ / 64, C_ / 64, B_), blk, 0, stream>>>(fused_t, featA, out);
}

// Round 11
// 213.442 us; speedup vs baseline: 1.0431x; 1.0431x over previous
//
#include <hip/hip_runtime.h>
#include <math.h>

#define B_ 2
#define N_ 2048
#define C_ 256
#define H_ 8
#define HD_ 32
constexpr float LN_EPS_ = 1e-5f;
constexpr float BN_EPS_ = 1e-5f;
constexpr float LOG2E_ = 1.4426950408889634f;
constexpr float ISDL_ = 0.17677669529663687f * 1.4426950408889634f; // 1/sqrt(32)*log2e

typedef __attribute__((ext_vector_type(8))) short bf16x8;
typedef __attribute__((ext_vector_type(4))) float f32x4;

static __device__ inline ushort f2bf(float x) {
    union { float f; uint u; } c{x};
    uint r = (c.u + 0x7FFF + ((c.u >> 16) & 1)) >> 16;
    return (ushort)r;
}
static __device__ inline float bf2f(ushort u) {
    union { uint i; float f; } c; c.i = ((uint)u) << 16; return c.f;
}
static __device__ inline float lane_bcast(float v, int srclane) {
    return __int_as_float(__builtin_amdgcn_ds_bpermute(srclane * 4, __float_as_int(v)));
}
// pack two f32 -> two bf16 (round-half-up): low16 = bf16(lo), high16 = bf16(hi)
static __device__ inline uint pack_bf2(float lo, float hi) {
    uint ul = __float_as_uint(lo) + 0x8000u;
    uint uh = __float_as_uint(hi) + 0x8000u;
    return __builtin_amdgcn_perm(uh, ul, 0x07060302u);
}

// ---------------------------------------------------------------------------
// 0. weight conversion f32 -> bf16. Layout (elements):
//    wq(0) wqd(65536) wk(131072) wkd(196608) wv(262144) wf1(327680) wf2(720896)
// ---------------------------------------------------------------------------
__global__ __launch_bounds__(256)
void k_wconv(const float* __restrict__ Wq, const float* __restrict__ Wqd,
             const float* __restrict__ Wk, const float* __restrict__ Wkd,
             const float* __restrict__ Wv, const float* __restrict__ Wf1,
             const float* __restrict__ Wf2, ushort* __restrict__ dst)
{
    size_t e0 = ((size_t)blockIdx.x * 256 + threadIdx.x) * 8;
    const float* src = Wq; size_t base = 0;
    if (e0 >= 65536)  { src = Wqd; base = 65536; }
    if (e0 >= 131072) { src = Wk;  base = 131072; }
    if (e0 >= 196608) { src = Wkd; base = 196608; }
    if (e0 >= 262144) { src = Wv;  base = 262144; }
    if (e0 >= 327680) { src = Wf1; base = 327680; }
    if (e0 >= 720896) { src = Wf2; base = 720896; }
    float4 a = *(const float4*)(src + (e0 - base));
    float4 b = *(const float4*)(src + (e0 - base) + 4);
    ushort o[8] = {f2bf(a.x), f2bf(a.y), f2bf(a.z), f2bf(a.w),
                   f2bf(b.x), f2bf(b.y), f2bf(b.z), f2bf(b.w)};
    *(uint4*)(dst + e0) = *(uint4*)o;
}

// 0b. bias concat for fused projections
__global__ __launch_bounds__(512)
void k_bconcat(const float* __restrict__ bq, const float* __restrict__ bqd,
               const float* __restrict__ bk, const float* __restrict__ bkd,
               float* __restrict__ bqqd, float* __restrict__ bkkd)
{
    int t = threadIdx.x;
    bqqd[t] = (t < 256) ? bq[t] : bqd[t - 256];
    bkkd[t] = (t < 256) ? bk[t] : bkd[t - 256];
}

// ---------------------------------------------------------------------------
// 1. LN-over-C with transpose: in [B,C,N] f32 -> bf16 rows [(b*N+n)*ld + c]
// ---------------------------------------------------------------------------
template<bool DO_LN>
__global__ __launch_bounds__(256)
void k_ln_transpose(const float* __restrict__ x,
                    const float* __restrict__ g,
                    const float* __restrict__ bt,
                    ushort* __restrict__ out, int ld)
{
    __shared__ float tile[C_][65];
    __shared__ float red_s[4][64];
    __shared__ float red_q[4][64];
    __shared__ float ms[64];
    __shared__ float rs[64];

    const int b  = blockIdx.x / (N_ / 64);
    const int n0 = (blockIdx.x % (N_ / 64)) * 64;
    const int tid = threadIdx.x;

    for (int i = 0; i < 64; ++i) {
        int c = i * 4 + (tid >> 6);
        int n = tid & 63;
        tile[c][n] = x[((size_t)b * C_ + c) * N_ + n0 + n];
    }
    __syncthreads();

    float gv = 0.f, bv = 0.f;
    if (DO_LN) { gv = g[tid]; bv = bt[tid]; }

    if (DO_LN) {
        const int nl = tid & 63, part = tid >> 6;
        float s = 0.f, q = 0.f;
        for (int j = 0; j < 64; ++j) {
            float v = tile[part * 64 + j][nl];
            s += v; q += v * v;
        }
        red_s[part][nl] = s; red_q[part][nl] = q;
        __syncthreads();
        if (tid < 64) {
            float ss = red_s[0][tid] + red_s[1][tid] + red_s[2][tid] + red_s[3][tid];
            float qq = red_q[0][tid] + red_q[1][tid] + red_q[2][tid] + red_q[3][tid];
            float mean = ss * (1.0f / C_);
            float var  = qq * (1.0f / C_) - mean * mean;
            ms[tid] = mean;
            rs[tid] = rsqrtf(var + LN_EPS_);
        }
        __syncthreads();
    }

    for (int i = 0; i < 64; ++i) {
        float v = tile[tid][i];
        if (DO_LN) v = (v - ms[i]) * rs[i] * gv + bv;
        out[((size_t)b * N_ + n0 + i) * ld + tid] = f2bf(v);
    }
}

// ---------------------------------------------------------------------------
// 2a. MFMA NT GEMM, 64x64 tile (kept for small-grid shapes: v^T, Wf2)
// ---------------------------------------------------------------------------
template<int EPI, int OUT>
__global__ __launch_bounds__(256)
void k_gemm_bf(const ushort* __restrict__ A, int lda, size_t sAz,
               const ushort* __restrict__ Bw, int ldb, size_t sBz,
               void* __restrict__ Cout_, int ldc, size_t sCz,
               int K,
               const float* __restrict__ aux1,
               const float* __restrict__ aux2)
{
    const int z = blockIdx.z;
    A  += (size_t)z * sAz;
    Bw += (size_t)z * sBz;

    const int r0 = blockIdx.x * 64;
    const int c0 = blockIdx.y * 64;
    const int tid = threadIdx.x;
    const int w = tid >> 6, lane = tid & 63;
    const int wr = w >> 1, wc = w & 1;
    const int ql = lane & 15, g = lane >> 4;

    __shared__ ushort As[64][40];
    __shared__ ushort Bs[64][40];

    f32x4 acc[2][2] = {};
    const int srow = tid >> 2;
    const int sk   = (tid & 3) * 8;

    for (int k0 = 0; k0 < K; k0 += 32) {
        bf16x8 av = *(const bf16x8*)&A[(size_t)(r0 + srow) * lda + k0 + sk];
        bf16x8 bv = *(const bf16x8*)&Bw[(size_t)(c0 + srow) * ldb + k0 + sk];
        __syncthreads();
        *(bf16x8*)&As[srow][sk] = av;
        *(bf16x8*)&Bs[srow][sk] = bv;
        __syncthreads();
        bf16x8 af[2], bf[2];
        #pragma unroll
        for (int i = 0; i < 2; ++i) {
            af[i] = *(const bf16x8*)&As[wr * 32 + i * 16 + ql][8 * g];
            bf[i] = *(const bf16x8*)&Bs[wc * 32 + i * 16 + ql][8 * g];
        }
        #pragma unroll
        for (int mi = 0; mi < 2; ++mi)
            #pragma unroll
            for (int ni = 0; ni < 2; ++ni)
                acc[mi][ni] = __builtin_amdgcn_mfma_f32_16x16x32_bf16(af[mi], bf[ni], acc[mi][ni], 0, 0, 0);
    }

    const float inv_bn = rsqrtf(1.0f + BN_EPS_);
    float*  Cf = (float*)Cout_  + (size_t)z * sCz;
    ushort* Cb = (ushort*)Cout_ + (size_t)z * sCz;
    #pragma unroll
    for (int mi = 0; mi < 2; ++mi) {
        #pragma unroll
        for (int ni = 0; ni < 2; ++ni) {
            #pragma unroll
            for (int r = 0; r < 4; ++r) {
                int row = r0 + wr * 32 + mi * 16 + 4 * g + r;
                int col = c0 + wc * 32 + ni * 16 + ql;
                float v = acc[mi][ni][r];
                if (EPI == 0) {
                    v += aux1[col];
                } else if (EPI == 1) {
                    float qnv = aux1[(size_t)z * N_ + row];
                    float knv = aux2[(size_t)z * N_ + col];
                    v = sqrtf(fmaxf(qnv + knv - 2.0f * v, 0.f));
                } else if (EPI == 2) {
                    v = fmaxf(v * (aux1[col] * inv_bn) + aux2[col], 0.f);
                } else if (EPI == 3) {
                    v += aux1[row];
                }
                if (OUT == 0) Cf[(size_t)row * ldc + col] = v;
                else          Cb[(size_t)row * ldc + col] = f2bf(v);
            }
        }
    }
}

// ---------------------------------------------------------------------------
// 2b. MFMA NT GEMM, 128xBN tile (BN=64 or 128): 4 waves (2x2 quadrants),
//     4 x (BN/32) fragments/wave, BK=32, reg-staged, padded LDS rows (72B)
//     so 16-lane fragment reads hit distinct bank-groups (18*ql mod 32 is a
//     permutation). BN=64 -> 8 MFMA/wave/K-step, 256-block grids for the
//     4096x512 shapes; BN=128 -> 16 MFMA, for cd (512 blocks).
// ---------------------------------------------------------------------------
template<int BN, int EPI, int OUT>
__global__ __launch_bounds__(256)
void k_gemm128(const ushort* __restrict__ A, int lda, size_t sAz,
               const ushort* __restrict__ Bw, int ldb, size_t sBz,
               void* __restrict__ Cout_, int ldc, size_t sCz,
               int K,
               const float* __restrict__ aux1,
               const float* __restrict__ aux2)
{
    constexpr int NF = BN / 32;          // col fragments per wave (2 or 4)
    const int z = blockIdx.z;
    A  += (size_t)z * sAz;
    Bw += (size_t)z * sBz;

    const int r0 = blockIdx.x * 128;
    const int c0 = blockIdx.y * BN;
    const int tid = threadIdx.x;
    const int w = tid >> 6, lane = tid & 63;
    const int wr = w >> 1, wc = w & 1;
    const int ql = lane & 15, g = lane >> 4;

    __shared__ ushort As[128][36];
    __shared__ ushort Bs[BN][36];

    f32x4 acc[4][NF] = {};
    const int srow = tid >> 2;          // 0..63
    const int sk   = (tid & 3) * 8;

    for (int k0 = 0; k0 < K; k0 += 32) {
        bf16x8 a0 = *(const bf16x8*)&A[(size_t)(r0 + srow) * lda + k0 + sk];
        bf16x8 a1 = *(const bf16x8*)&A[(size_t)(r0 + 64 + srow) * lda + k0 + sk];
        bf16x8 b0 = *(const bf16x8*)&Bw[(size_t)(c0 + srow) * ldb + k0 + sk];
        bf16x8 b1;
        if (BN == 128) b1 = *(const bf16x8*)&Bw[(size_t)(c0 + 64 + srow) * ldb + k0 + sk];
        __syncthreads();                 // prior frag reads done
        *(bf16x8*)&As[srow][sk]      = a0;
        *(bf16x8*)&As[64 + srow][sk] = a1;
        *(bf16x8*)&Bs[srow][sk]      = b0;
        if (BN == 128) *(bf16x8*)&Bs[64 + srow][sk] = b1;
        __syncthreads();
        bf16x8 af[4], bf[NF];
        #pragma unroll
        for (int i = 0; i < 4; ++i)
            af[i] = *(const bf16x8*)&As[wr * 64 + i * 16 + ql][8 * g];
        #pragma unroll
        for (int i = 0; i < NF; ++i)
            bf[i] = *(const bf16x8*)&Bs[wc * (BN / 2) + i * 16 + ql][8 * g];
        #pragma unroll
        for (int mi = 0; mi < 4; ++mi)
            #pragma unroll
            for (int ni = 0; ni < NF; ++ni)
                acc[mi][ni] = __builtin_amdgcn_mfma_f32_16x16x32_bf16(af[mi], bf[ni], acc[mi][ni], 0, 0, 0);
    }

    const float inv_bn = rsqrtf(1.0f + BN_EPS_);
    float*  Cf = (float*)Cout_  + (size_t)z * sCz;
    ushort* Cb = (ushort*)Cout_ + (size_t)z * sCz;
    #pragma unroll
    for (int mi = 0; mi < 4; ++mi) {
        #pragma unroll
        for (int ni = 0; ni < NF; ++ni) {
            #pragma unroll
            for (int r = 0; r < 4; ++r) {
                int row = r0 + wr * 64 + mi * 16 + 4 * g + r;
                int col = c0 + wc * (BN / 2) + ni * 16 + ql;
                float v = acc[mi][ni][r];
                if (EPI == 0) {
                    v += aux1[col];
                } else if (EPI == 1) {
                    float qnv = aux1[(size_t)z * N_ + row];
                    float knv = aux2[(size_t)z * N_ + col];
                    v = sqrtf(fmaxf(qnv + knv - 2.0f * v, 0.f));
                } else if (EPI == 2) {
                    v = fmaxf(v * (aux1[col] * inv_bn) + aux2[col], 0.f);
                } else if (EPI == 3) {
                    v += aux1[row];
                }
                if (OUT == 0) Cf[(size_t)row * ldc + col] = v;
                else          Cb[(size_t)row * ldc + col] = f2bf(v);
            }
        }
    }
}

// ---------------------------------------------------------------------------
// 3. row squared-norm over bf16 rows [R,256] with row stride ld
// ---------------------------------------------------------------------------
__global__ __launch_bounds__(256)
void k_rownorm(const ushort* __restrict__ x, int ld, float* __restrict__ outn)
{
    const int r = blockIdx.x * 4 + (threadIdx.x >> 6);
    const int lane = threadIdx.x & 63;
    uint2 pv = *(const uint2*)&x[(size_t)r * ld + lane * 4];
    float v0 = bf2f((ushort)(pv.x & 0xffff)), v1 = bf2f((ushort)(pv.x >> 16));
    float v2 = bf2f((ushort)(pv.y & 0xffff)), v3 = bf2f((ushort)(pv.y >> 16));
    float s = v0 * v0 + v1 * v1 + v2 * v2 + v3 * v3;
    #pragma unroll
    for (int off = 32; off; off >>= 1) s += __shfl_xor(s, off);
    if (lane == 0) outn[r] = s;
}

// ---------------------------------------------------------------------------
// 4. fused attention v5: split-m + split-head. 512 thr = 8 waves =
//    (2 paths x 4 heads). grid (N/16, B, 2 half x 2 head-group).
// ---------------------------------------------------------------------------
#define QLD_ 512
__global__ __launch_bounds__(512, 4)
void k_attn5(const ushort* __restrict__ q_bf,  // [B*N][512] (cols 0..255 = q)
             const ushort* __restrict__ k_bf,  // [B*N][512] (cols 0..255 = k)
             const ushort* __restrict__ v_c,   // [B][256][N]
             const float* __restrict__ xyzA,   // [B][N][3]
             const float* __restrict__ xyzB,   // [B][N][3]
             const ushort* __restrict__ cdb,   // [B][N][N] bf16
             const float* __restrict__ sb_w1, const float* __restrict__ sb_bn_g,
             const float* __restrict__ sb_bn_b, const float* __restrict__ sb_w2,
             const float* __restrict__ sb_b2,
             ushort* __restrict__ pc,          // [half*2+path][B*N][256] bf16
             float* __restrict__ pml)          // [half*2+path][B*N][H][2]
{
    __shared__ ushort biasL[4][16][72];   // [local h][q][m] bf16 (log2e domain)
    __shared__ float  cds[16][68];        // [q][m] cd*log2e
    __shared__ ushort ps[8][16][72];      // per-wave P (bf16)
    __shared__ float  w2Ls[4][4];         // local head weights (log2e-scaled)
    __shared__ float  b2Ls[4];

    const int n0 = blockIdx.x * 16;
    const int b  = blockIdx.y;
    const int hg   = blockIdx.z & 1;      // head group: heads hg*4 .. hg*4+3
    const int half = blockIdx.z >> 1;     // m-range half
    const size_t bN = (size_t)b * N_;
    const int tid = threadIdx.x;
    const int w = tid >> 6, lane = tid & 63;
    const int path = w >> 2, hl = w & 3;
    const int h = hg * 4 + hl;
    const int ql = lane & 15, g = lane >> 4;

    if (tid < 4) {
        b2Ls[tid] = sb_b2[hg * 4 + tid] * LOG2E_;
        #pragma unroll
        for (int i = 0; i < 4; ++i) w2Ls[tid][i] = sb_w2[(hg * 4 + tid) * 4 + i] * LOG2E_;
    }

    const float inv_bn = rsqrtf(1.0f + BN_EPS_);
    float w1s_[4], bnb_[4];
    #pragma unroll
    for (int i = 0; i < 4; ++i) {
        w1s_[i] = sb_w1[i] * sb_bn_g[i] * inv_bn;
        bnb_[i] = sb_bn_b[i];
    }

    // coop indices: 512 threads = 16 q x 32 m-pairs
    const int cq = tid >> 5, cm2 = tid & 31;
    const float ax = xyzA[(bN + n0 + cq) * 3 + 0];
    const float ay = xyzA[(bN + n0 + cq) * 3 + 1];
    const float az = xyzA[(bN + n0 + cq) * 3 + 2];

    bf16x8 qfrag = {};
    if (path == 0)
        qfrag = *(const bf16x8*)&q_bf[(bN + n0 + ql) * QLD_ + h * 32 + 8 * g];

    float m_i = -INFINITY, l_i = 0.f;
    f32x4 ctx0 = {0.f, 0.f, 0.f, 0.f};
    f32x4 ctx1 = {0.f, 0.f, 0.f, 0.f};
    const f32x4 zf = {0.f, 0.f, 0.f, 0.f};

    const int tBeg = half * (N_ / 128);          // 16 tiles per half
    const int tEnd = tBeg + (N_ / 128);

    for (int t = tBeg; t < tEnd; ++t) {
        const int m0 = t * 64;
        __syncthreads();   // prior tile's LDS reads done (also covers w2Ls init)

        // ---- coop: bias[4][16][64] bf16 + cds ----
        {
            const int mA = m0 + 2 * cm2;
            const float* pb = xyzB + (bN + mA) * 3;
            float bx0 = pb[0], by0 = pb[1], bz0 = pb[2];
            float bx1 = pb[3], by1 = pb[4], bz1 = pb[5];
            float dx0 = ax - bx0, dy0 = ay - by0, dz0 = az - bz0;
            float dx1 = ax - bx1, dy1 = ay - by1, dz1 = az - bz1;
            float d0 = sqrtf(dx0 * dx0 + dy0 * dy0 + dz0 * dz0);
            float d1 = sqrtf(dx1 * dx1 + dy1 * dy1 + dz1 * dz1);
            float f0[4], f1[4];
            #pragma unroll
            for (int i = 0; i < 4; ++i) {
                f0[i] = fmaxf(fmaf(-w1s_[i], d0, bnb_[i]), 0.f);
                f1[i] = fmaxf(fmaf(-w1s_[i], d1, bnb_[i]), 0.f);
            }
            #pragma unroll
            for (int hh = 0; hh < 4; ++hh) {
                const f32x4 w2v = *(const f32x4*)w2Ls[hh];
                float b0 = b2Ls[hh], b1 = b2Ls[hh];
                #pragma unroll
                for (int i = 0; i < 4; ++i) {
                    b0 = fmaf(w2v[i], f0[i], b0);
                    b1 = fmaf(w2v[i], f1[i], b1);
                }
                *(uint*)&biasL[hh][cq][2 * cm2] = pack_bf2(b0, b1);
            }
            uint cv = *(const uint*)&cdb[(bN + n0 + cq) * (size_t)N_ + mA];
            cds[cq][2 * cm2]     = bf2f((ushort)(cv & 0xffff)) * LOG2E_;
            cds[cq][2 * cm2 + 1] = bf2f((ushort)(cv >> 16)) * LOG2E_;
        }
        __syncthreads();

        // ---- per-wave: issue global loads early ----
        bf16x8 af[4];
        if (path == 0) {
            #pragma unroll
            for (int mt = 0; mt < 4; ++mt)
                af[mt] = *(const bf16x8*)&k_bf[(bN + m0 + mt * 16 + ql) * QLD_ + h * 32 + 8 * g];
        }
        bf16x8 vb[2][2];
        #pragma unroll
        for (int kb = 0; kb < 2; ++kb)
            #pragma unroll
            for (int dt = 0; dt < 2; ++dt)
                vb[kb][dt] = *(const bf16x8*)&v_c[((size_t)b * C_ + h * 32 + dt * 16 + ql) * N_ + m0 + kb * 32 + 8 * g];

        // ---- s init from bias LDS ----
        float s[16];
        #pragma unroll
        for (int mt = 0; mt < 4; ++mt) {
            uint2 bw = *(const uint2*)&biasL[hl][ql][16 * mt + 4 * g];
            s[4 * mt + 0] = __uint_as_float(bw.x << 16);
            s[4 * mt + 1] = __uint_as_float(bw.x & 0xffff0000u);
            s[4 * mt + 2] = __uint_as_float(bw.y << 16);
            s[4 * mt + 3] = __uint_as_float(bw.y & 0xffff0000u);
        }

        if (path == 0) {
            #pragma unroll
            for (int mt = 0; mt < 4; ++mt) {
                f32x4 sf = __builtin_amdgcn_mfma_f32_16x16x32_bf16(af[mt], qfrag, zf, 0, 0, 0);
                #pragma unroll
                for (int r = 0; r < 4; ++r)
                    s[4 * mt + r] = fmaf(sf[r], ISDL_, s[4 * mt + r]);
            }
        } else {
            #pragma unroll
            for (int mt = 0; mt < 4; ++mt) {
                f32x4 cv = *(const f32x4*)&cds[ql][16 * mt + 4 * g];
                #pragma unroll
                for (int r = 0; r < 4; ++r)
                    s[4 * mt + r] += cv[r];
            }
        }

        // ---- online softmax with defer-max ----
        float tmax = s[0];
        #pragma unroll
        for (int j = 1; j < 16; ++j) tmax = fmaxf(tmax, s[j]);
        tmax = fmaxf(tmax, __shfl_xor(tmax, 16));
        tmax = fmaxf(tmax, __shfl_xor(tmax, 32));
        if (!__all(tmax <= m_i + 8.0f)) {
            float mnew = fmaxf(m_i, tmax);
            float scl = exp2f(m_i - mnew);
            l_i *= scl;
            #pragma unroll
            for (int r = 0; r < 4; ++r) {
                float sr = lane_bcast(scl, 4 * g + r);
                ctx0[r] *= sr; ctx1[r] *= sr;
            }
            m_i = mnew;
        }
        float lsum = 0.f;
        #pragma unroll
        for (int j = 0; j < 16; ++j) {
            float pj = exp2f(s[j] - m_i);
            s[j] = pj;
            lsum += pj;
        }
        lsum += __shfl_xor(lsum, 16);
        lsum += __shfl_xor(lsum, 32);
        l_i += lsum;

        // ---- pack P -> per-wave LDS ----
        #pragma unroll
        for (int mt = 0; mt < 4; ++mt) {
            uint2 pk;
            pk.x = pack_bf2(s[4 * mt + 0], s[4 * mt + 1]);
            pk.y = pack_bf2(s[4 * mt + 2], s[4 * mt + 3]);
            *(uint2*)&ps[w][ql][16 * mt + 4 * g] = pk;
        }

        // ---- PV ----
        #pragma unroll
        for (int kb = 0; kb < 2; ++kb) {
            bf16x8 pa = *(const bf16x8*)&ps[w][ql][kb * 32 + 8 * g];
            ctx0 = __builtin_amdgcn_mfma_f32_16x16x32_bf16(pa, vb[kb][0], ctx0, 0, 0, 0);
            ctx1 = __builtin_amdgcn_mfma_f32_16x16x32_bf16(pa, vb[kb][1], ctx1, 0, 0, 0);
        }
    }

    // ---- epilogue: unnormalized partial ctx (bf16) + (m,l) ----
    const size_t sl = (size_t)(half * 2 + path) * (B_ * N_);
    #pragma unroll
    for (int r = 0; r < 4; ++r) {
        size_t base = (sl + bN + n0 + 4 * g + r) * C_ + h * 32;
        pc[base + ql]      = f2bf(ctx0[r]);
        pc[base + 16 + ql] = f2bf(ctx1[r]);
    }
    if (g == 0) {
        size_t mlb = ((sl + bN + n0 + ql) * H_ + h) * 2;
        pml[mlb]     = m_i;
        pml[mlb + 1] = l_i;
    }
}

// ---------------------------------------------------------------------------
// 5. merge halves + LayerNorm, write bf16 into fused_bf columns.
// ---------------------------------------------------------------------------
__global__ __launch_bounds__(256)
void k_merge_ln(const ushort* __restrict__ pc, const float* __restrict__ pml,
                const float* __restrict__ g_sim, const float* __restrict__ b_sim,
                const float* __restrict__ g_dis, const float* __restrict__ b_dis,
                ushort* __restrict__ fused_bf)
{
    __shared__ float rs_[4], rq_[4];
    const int row = blockIdx.x;           // global row in [0, B*N)
    const int path = blockIdx.y;
    const int c = threadIdx.x;
    const int h = c >> 5;
    const size_t i0 = (size_t)(0 * 2 + path) * (B_ * N_) + row;
    const size_t i1 = (size_t)(1 * 2 + path) * (B_ * N_) + row;
    const float m0 = pml[(i0 * H_ + h) * 2], l0 = pml[(i0 * H_ + h) * 2 + 1];
    const float m1 = pml[(i1 * H_ + h) * 2], l1 = pml[(i1 * H_ + h) * 2 + 1];
    const float M = fmaxf(m0, m1);
    const float w0 = exp2f(m0 - M), w1 = exp2f(m1 - M);
    const float il = 1.0f / fmaf(l0, w0, l1 * w1);
    const float v = fmaf(bf2f(pc[i0 * C_ + c]), w0, bf2f(pc[i1 * C_ + c]) * w1) * il;

    float s = v, q = v * v;
    #pragma unroll
    for (int off = 32; off; off >>= 1) { s += __shfl_xor(s, off); q += __shfl_xor(q, off); }
    const int wv = c >> 6, lane = c & 63;
    if (lane == 0) { rs_[wv] = s; rq_[wv] = q; }
    __syncthreads();
    float ss = rs_[0] + rs_[1] + rs_[2] + rs_[3];
    float qq = rq_[0] + rq_[1] + rq_[2] + rq_[3];
    float mean = ss * (1.0f / C_);
    float var  = qq * (1.0f / C_) - mean * mean;
    float rstd = rsqrtf(var + LN_EPS_);
    const float* gp = path ? g_dis : g_sim;
    const float* bp = path ? b_dis : b_sim;
    fused_bf[(size_t)row * (3 * C_) + C_ + path * C_ + c] =
        f2bf((v - mean) * rstd * gp[c] + bp[c]);
}

// ---------------------------------------------------------------------------
// 6. transpose [B*N,256] f32 -> [B,C,N] and add residual featA
// ---------------------------------------------------------------------------
__global__ __launch_bounds__(256)
void k_transpose_add(const float* __restrict__ fused_t,
                     const float* __restrict__ featA,
                     float* __restrict__ out)
{
    __shared__ float t[64][65];
    const int n0 = blockIdx.x * 64, c0 = blockIdx.y * 64, b = blockIdx.z;
    const int tid = threadIdx.x;
    #pragma unroll
    for (int i = 0; i < 16; ++i) {
        int e = i * 256 + tid;
        int nn = e >> 6, cc = e & 63;
        t[nn][cc] = fused_t[((size_t)b * N_ + n0 + nn) * C_ + c0 + cc];
    }
    __syncthreads();
    #pragma unroll
    for (int i = 0; i < 16; ++i) {
        int e = i * 256 + tid;
        int cc = e >> 6, nn = e & 63;
        size_t idx = ((size_t)b * C_ + c0 + cc) * N_ + n0 + nn;
        out[idx] = t[nn][cc] + featA[idx];
    }
}

// ---------------------------------------------------------------------------
extern "C" void kernel_launch(void* const* d_in, const int* in_sizes, int n_in,
                              void* d_out, int out_size, void* d_ws, size_t ws_size,
                              hipStream_t stream)
{
    const float* xyz_A   = (const float*)d_in[0];
    const float* featA   = (const float*)d_in[1];
    const float* xyz_B   = (const float*)d_in[2];
    const float* featB   = (const float*)d_in[3];
    const float* ln_in_g = (const float*)d_in[4];
    const float* ln_in_b = (const float*)d_in[5];
    const float* Wq  = (const float*)d_in[6];
    const float* bq  = (const float*)d_in[7];
    const float* Wk  = (const float*)d_in[8];
    const float* bk  = (const float*)d_in[9];
    const float* Wv  = (const float*)d_in[10];
    const float* bv  = (const float*)d_in[11];
    const float* sb_w1   = (const float*)d_in[12];
    const float* sb_bn_g = (const float*)d_in[13];
    const float* sb_bn_b = (const float*)d_in[14];
    const float* sb_w2   = (const float*)d_in[15];
    const float* sb_b2   = (const float*)d_in[16];
    const float* Wqd = (const float*)d_in[17];
    const float* bqd = (const float*)d_in[18];
    const float* Wkd = (const float*)d_in[19];
    const float* bkd = (const float*)d_in[20];
    const float* ln_sim_g = (const float*)d_in[21];
    const float* ln_sim_b = (const float*)d_in[22];
    const float* ln_dis_g = (const float*)d_in[23];
    const float* ln_dis_b = (const float*)d_in[24];
    const float* Wf1   = (const float*)d_in[25];
    const float* bnf_g = (const float*)d_in[26];
    const float* bnf_b = (const float*)d_in[27];
    const float* Wf2   = (const float*)d_in[28];
    const float* bf2   = (const float*)d_in[29];
    float* out = (float*)d_out;

    float* ws = (float*)d_ws;
    size_t off = 0;
    auto alloc = [&](size_t n) { float* p = ws + off; off += n; return p; };
    const size_t RN = (size_t)B_ * N_;   // 4096 rows

    ushort* fused_bf = (ushort*)alloc(RN * 384);       // [RN][768] bf16
    ushort* featB_bf = (ushort*)alloc(RN * 128);       // [RN][256] bf16
    ushort* qqd_bf   = (ushort*)alloc(RN * 256);       // [RN][512] bf16 (q|qd)
    ushort* kkd_bf   = (ushort*)alloc(RN * 256);       // [RN][512] bf16 (k|kd)
    ushort* v_bf     = (ushort*)alloc(RN * 128);       // [B][256][N] bf16
    ushort* wbf      = (ushort*)alloc(425984);         // 851968 bf16 weights
    float*  bqqd     = alloc(512);
    float*  bkkd     = alloc(512);
    float*  qn       = alloc(RN);
    float*  kn       = alloc(RN);
    ushort* cd_bf    = (ushort*)alloc((size_t)B_ * N_ * N_ / 2); // bf16; reused fh+fused_t
    ushort* pc       = (ushort*)alloc(4 * RN * C_ / 2);// [4][RN][256] bf16 partial ctx
    float*  pml      = alloc(4 * RN * H_ * 2);         // [4][RN][H][2]

    ushort* q_bf  = qqd_bf;            // stride 512, cols 0..255
    ushort* qd_bf = qqd_bf + 256;      // stride 512
    ushort* k_bf  = kkd_bf;
    ushort* kd_bf = kkd_bf + 256;
    ushort* fh      = cd_bf;                            // [RN][512] bf16 (cd dead after attn)
    float*  fused_t = (float*)(cd_bf + (size_t)RN * 512); // f32 [RN][256]

    ushort* wqqd_bf = wbf;             // [512][256]
    ushort* wkkd_bf = wbf + 131072;    // [512][256]
    ushort* wv_bf   = wbf + 262144;
    ushort* wf1_bf  = wbf + 327680;
    ushort* wf2_bf  = wbf + 720896;
    (void)ws_size; (void)in_sizes; (void)n_in; (void)out_size;

    dim3 blk(256);

    // 0) weights -> bf16 ; biases concat ; 1) LN/transpose -> bf16
    k_wconv<<<dim3(416), blk, 0, stream>>>(Wq, Wqd, Wk, Wkd, Wv, Wf1, Wf2, wbf);
    k_bconcat<<<dim3(1), dim3(512), 0, stream>>>(bq, bqd, bk, bkd, bqqd, bkkd);
    k_ln_transpose<true ><<<dim3(B_ * (N_ / 64)), blk, 0, stream>>>(featA, ln_in_g, ln_in_b, fused_bf, 3 * C_);
    k_ln_transpose<false><<<dim3(B_ * (N_ / 64)), blk, 0, stream>>>(featB, nullptr, nullptr, featB_bf, C_);

    // 2) fused projections: q|qd, k|kd on 128x64 (256 blocks); v^T on 64^2
    k_gemm128<64,0,1><<<dim3(RN / 128, 8, 1), blk, 0, stream>>>(fused_bf, 3 * C_, 0, wqqd_bf, C_, 0, qqd_bf, 512, 0, C_, bqqd, nullptr);
    k_gemm128<64,0,1><<<dim3(RN / 128, 8, 1), blk, 0, stream>>>(featB_bf, C_,     0, wkkd_bf, C_, 0, kkd_bf, 512, 0, C_, bkkd, nullptr);
    k_gemm_bf<3,1><<<dim3(C_ / 64, N_ / 64, B_), blk, 0, stream>>>(wv_bf, C_, 0, featB_bf, C_, (size_t)N_ * C_, v_bf, N_, (size_t)C_ * N_, C_, bv, nullptr);

    // 3) feature-cdist (bf16 out, 128x128 tile -> 512 blocks)
    k_rownorm<<<dim3(RN / 4), blk, 0, stream>>>(qd_bf, 512, qn);
    k_rownorm<<<dim3(RN / 4), blk, 0, stream>>>(kd_bf, 512, kn);
    k_gemm128<128,1,1><<<dim3(N_ / 128, N_ / 128, B_), blk, 0, stream>>>(qd_bf, 512, (size_t)N_ * 512,
                                                                         kd_bf, 512, (size_t)N_ * 512,
                                                                         cd_bf, N_, (size_t)N_ * N_, C_, qn, kn);

    // 4) fused attention v5 (split-m + split-head) + fused merge+LN
    k_attn5<<<dim3(N_ / 16, B_, 4), dim3(512), 0, stream>>>(q_bf, k_bf, v_bf, xyz_A, xyz_B, cd_bf,
                                                            sb_w1, sb_bn_g, sb_bn_b, sb_w2, sb_b2,
                                                            pc, pml);
    k_merge_ln<<<dim3(RN, 2), blk, 0, stream>>>(pc, pml, ln_sim_g, ln_sim_b, ln_dis_g, ln_dis_b, fused_bf);

    // 5) fused MLP: Wf1 on 128x64 (256 blocks), Wf2 on 64^2
    k_gemm128<64,2,1><<<dim3(RN / 128, 8, 1), blk, 0, stream>>>(fused_bf, 3 * C_, 0, wf1_bf, 3 * C_, 0, fh, 2 * C_, 0, 3 * C_, bnf_g, bnf_b);
    k_gemm_bf<0,0><<<dim3(RN / 64, C_ / 64, 1), blk, 0, stream>>>(fh, 2 * C_, 0, wf2_bf, 2 * C_, 0, fused_t, C_, 0, 2 * C_, bf2, nullptr);

    // 6) transpose + residual
    k_transpose_add<<<dim3(N_ / 64, C_ / 64, B_), blk, 0, stream>>>(fused_t, featA, out);
}

// Round 12
// 207.496 us; speedup vs baseline: 1.0730x; 1.0287x over previous
//
#include <hip/hip_runtime.h>
#include <math.h>

#define B_ 2
#define N_ 2048
#define C_ 256
#define H_ 8
#define HD_ 32
constexpr float LN_EPS_ = 1e-5f;
constexpr float BN_EPS_ = 1e-5f;
constexpr float LOG2E_ = 1.4426950408889634f;
constexpr float ISDL_ = 0.17677669529663687f * 1.4426950408889634f; // 1/sqrt(32)*log2e

typedef __attribute__((ext_vector_type(8))) short bf16x8;
typedef __attribute__((ext_vector_type(4))) float f32x4;

static __device__ inline ushort f2bf(float x) {
    union { float f; uint u; } c{x};
    uint r = (c.u + 0x7FFF + ((c.u >> 16) & 1)) >> 16;
    return (ushort)r;
}
static __device__ inline float bf2f(ushort u) {
    union { uint i; float f; } c; c.i = ((uint)u) << 16; return c.f;
}
static __device__ inline float lane_bcast(float v, int srclane) {
    return __int_as_float(__builtin_amdgcn_ds_bpermute(srclane * 4, __float_as_int(v)));
}
// pack two f32 -> two bf16 (round-half-up): low16 = bf16(lo), high16 = bf16(hi)
static __device__ inline uint pack_bf2(float lo, float hi) {
    uint ul = __float_as_uint(lo) + 0x8000u;
    uint uh = __float_as_uint(hi) + 0x8000u;
    return __builtin_amdgcn_perm(uh, ul, 0x07060302u);
}

// ---------------------------------------------------------------------------
// 0. weight conversion f32 -> bf16. Layout (elements):
//    wq(0) wqd(65536) wk(131072) wkd(196608) wv(262144) wf1(327680) wf2(720896)
// ---------------------------------------------------------------------------
__global__ __launch_bounds__(256)
void k_wconv(const float* __restrict__ Wq, const float* __restrict__ Wqd,
             const float* __restrict__ Wk, const float* __restrict__ Wkd,
             const float* __restrict__ Wv, const float* __restrict__ Wf1,
             const float* __restrict__ Wf2, ushort* __restrict__ dst)
{
    size_t e0 = ((size_t)blockIdx.x * 256 + threadIdx.x) * 8;
    const float* src = Wq; size_t base = 0;
    if (e0 >= 65536)  { src = Wqd; base = 65536; }
    if (e0 >= 131072) { src = Wk;  base = 131072; }
    if (e0 >= 196608) { src = Wkd; base = 196608; }
    if (e0 >= 262144) { src = Wv;  base = 262144; }
    if (e0 >= 327680) { src = Wf1; base = 327680; }
    if (e0 >= 720896) { src = Wf2; base = 720896; }
    float4 a = *(const float4*)(src + (e0 - base));
    float4 b = *(const float4*)(src + (e0 - base) + 4);
    ushort o[8] = {f2bf(a.x), f2bf(a.y), f2bf(a.z), f2bf(a.w),
                   f2bf(b.x), f2bf(b.y), f2bf(b.z), f2bf(b.w)};
    *(uint4*)(dst + e0) = *(uint4*)o;
}

// 0b. bias concat for fused projections
__global__ __launch_bounds__(512)
void k_bconcat(const float* __restrict__ bq, const float* __restrict__ bqd,
               const float* __restrict__ bk, const float* __restrict__ bkd,
               float* __restrict__ bqqd, float* __restrict__ bkkd)
{
    int t = threadIdx.x;
    bqqd[t] = (t < 256) ? bq[t] : bqd[t - 256];
    bkkd[t] = (t < 256) ? bk[t] : bkd[t - 256];
}

// ---------------------------------------------------------------------------
// 1. LN-over-C with transpose: in [B,C,N] f32 -> bf16 rows [(b*N+n)*ld + c]
// ---------------------------------------------------------------------------
template<bool DO_LN>
__global__ __launch_bounds__(256)
void k_ln_transpose(const float* __restrict__ x,
                    const float* __restrict__ g,
                    const float* __restrict__ bt,
                    ushort* __restrict__ out, int ld)
{
    __shared__ float tile[C_][65];
    __shared__ float red_s[4][64];
    __shared__ float red_q[4][64];
    __shared__ float ms[64];
    __shared__ float rs[64];

    const int b  = blockIdx.x / (N_ / 64);
    const int n0 = (blockIdx.x % (N_ / 64)) * 64;
    const int tid = threadIdx.x;

    for (int i = 0; i < 64; ++i) {
        int c = i * 4 + (tid >> 6);
        int n = tid & 63;
        tile[c][n] = x[((size_t)b * C_ + c) * N_ + n0 + n];
    }
    __syncthreads();

    float gv = 0.f, bv = 0.f;
    if (DO_LN) { gv = g[tid]; bv = bt[tid]; }

    if (DO_LN) {
        const int nl = tid & 63, part = tid >> 6;
        float s = 0.f, q = 0.f;
        for (int j = 0; j < 64; ++j) {
            float v = tile[part * 64 + j][nl];
            s += v; q += v * v;
        }
        red_s[part][nl] = s; red_q[part][nl] = q;
        __syncthreads();
        if (tid < 64) {
            float ss = red_s[0][tid] + red_s[1][tid] + red_s[2][tid] + red_s[3][tid];
            float qq = red_q[0][tid] + red_q[1][tid] + red_q[2][tid] + red_q[3][tid];
            float mean = ss * (1.0f / C_);
            float var  = qq * (1.0f / C_) - mean * mean;
            ms[tid] = mean;
            rs[tid] = rsqrtf(var + LN_EPS_);
        }
        __syncthreads();
    }

    for (int i = 0; i < 64; ++i) {
        float v = tile[tid][i];
        if (DO_LN) v = (v - ms[i]) * rs[i] * gv + bv;
        out[((size_t)b * N_ + n0 + i) * ld + tid] = f2bf(v);
    }
}

// ---------------------------------------------------------------------------
// 2. MFMA NT GEMM, 64x64 tile, 4 waves, BK=32 (the R8-proven config).
//    EPI 0:+aux1[col]; 1: cdist sqrt * LOG2E (log2e-domain cd for attn);
//    2: BN+relu; 3:+aux1[row].  OUT 0: f32 store; 1: bf16 store.
// ---------------------------------------------------------------------------
template<int EPI, int OUT>
__global__ __launch_bounds__(256)
void k_gemm_bf(const ushort* __restrict__ A, int lda, size_t sAz,
               const ushort* __restrict__ Bw, int ldb, size_t sBz,
               void* __restrict__ Cout_, int ldc, size_t sCz,
               int K,
               const float* __restrict__ aux1,
               const float* __restrict__ aux2)
{
    const int z = blockIdx.z;
    A  += (size_t)z * sAz;
    Bw += (size_t)z * sBz;

    const int r0 = blockIdx.x * 64;
    const int c0 = blockIdx.y * 64;
    const int tid = threadIdx.x;
    const int w = tid >> 6, lane = tid & 63;
    const int wr = w >> 1, wc = w & 1;
    const int ql = lane & 15, g = lane >> 4;

    __shared__ ushort As[64][40];
    __shared__ ushort Bs[64][40];

    f32x4 acc[2][2] = {};
    const int srow = tid >> 2;
    const int sk   = (tid & 3) * 8;

    for (int k0 = 0; k0 < K; k0 += 32) {
        bf16x8 av = *(const bf16x8*)&A[(size_t)(r0 + srow) * lda + k0 + sk];
        bf16x8 bv = *(const bf16x8*)&Bw[(size_t)(c0 + srow) * ldb + k0 + sk];
        __syncthreads();
        *(bf16x8*)&As[srow][sk] = av;
        *(bf16x8*)&Bs[srow][sk] = bv;
        __syncthreads();
        bf16x8 af[2], bf[2];
        #pragma unroll
        for (int i = 0; i < 2; ++i) {
            af[i] = *(const bf16x8*)&As[wr * 32 + i * 16 + ql][8 * g];
            bf[i] = *(const bf16x8*)&Bs[wc * 32 + i * 16 + ql][8 * g];
        }
        #pragma unroll
        for (int mi = 0; mi < 2; ++mi)
            #pragma unroll
            for (int ni = 0; ni < 2; ++ni)
                acc[mi][ni] = __builtin_amdgcn_mfma_f32_16x16x32_bf16(af[mi], bf[ni], acc[mi][ni], 0, 0, 0);
    }

    const float inv_bn = rsqrtf(1.0f + BN_EPS_);
    float*  Cf = (float*)Cout_  + (size_t)z * sCz;
    ushort* Cb = (ushort*)Cout_ + (size_t)z * sCz;
    #pragma unroll
    for (int mi = 0; mi < 2; ++mi) {
        #pragma unroll
        for (int ni = 0; ni < 2; ++ni) {
            #pragma unroll
            for (int r = 0; r < 4; ++r) {
                int row = r0 + wr * 32 + mi * 16 + 4 * g + r;
                int col = c0 + wc * 32 + ni * 16 + ql;
                float v = acc[mi][ni][r];
                if (EPI == 0) {
                    v += aux1[col];
                } else if (EPI == 1) {
                    float qnv = aux1[(size_t)z * N_ + row];
                    float knv = aux2[(size_t)z * N_ + col];
                    v = sqrtf(fmaxf(qnv + knv - 2.0f * v, 0.f)) * LOG2E_;
                } else if (EPI == 2) {
                    v = fmaxf(v * (aux1[col] * inv_bn) + aux2[col], 0.f);
                } else if (EPI == 3) {
                    v += aux1[row];
                }
                if (OUT == 0) Cf[(size_t)row * ldc + col] = v;
                else          Cb[(size_t)row * ldc + col] = f2bf(v);
            }
        }
    }
}

// ---------------------------------------------------------------------------
// 3. row squared-norm over bf16 rows [R,256] with row stride ld
// ---------------------------------------------------------------------------
__global__ __launch_bounds__(256)
void k_rownorm(const ushort* __restrict__ x, int ld, float* __restrict__ outn)
{
    const int r = blockIdx.x * 4 + (threadIdx.x >> 6);
    const int lane = threadIdx.x & 63;
    uint2 pv = *(const uint2*)&x[(size_t)r * ld + lane * 4];
    float v0 = bf2f((ushort)(pv.x & 0xffff)), v1 = bf2f((ushort)(pv.x >> 16));
    float v2 = bf2f((ushort)(pv.y & 0xffff)), v3 = bf2f((ushort)(pv.y >> 16));
    float s = v0 * v0 + v1 * v1 + v2 * v2 + v3 * v3;
    #pragma unroll
    for (int off = 32; off; off >>= 1) s += __shfl_xor(s, off);
    if (lane == 0) outn[r] = s;
}

// ---------------------------------------------------------------------------
// 4. fused attention v6: split-m + split-head. 512 thr = 8 waves =
//    (2 paths x 4 heads). grid (N/16, B, 2 half x 2 head-group).
//    biasL stored f32 (no pack/unpack); cdb already log2e-scaled by GEMM.
// ---------------------------------------------------------------------------
#define QLD_ 512
__global__ __launch_bounds__(512, 4)
void k_attn6(const ushort* __restrict__ q_bf,  // [B*N][512] (cols 0..255 = q)
             const ushort* __restrict__ k_bf,  // [B*N][512] (cols 0..255 = k)
             const ushort* __restrict__ v_c,   // [B][256][N]
             const float* __restrict__ xyzA,   // [B][N][3]
             const float* __restrict__ xyzB,   // [B][N][3]
             const ushort* __restrict__ cdb,   // [B][N][N] bf16, log2e-domain
             const float* __restrict__ sb_w1, const float* __restrict__ sb_bn_g,
             const float* __restrict__ sb_bn_b, const float* __restrict__ sb_w2,
             const float* __restrict__ sb_b2,
             ushort* __restrict__ pc,          // [half*2+path][B*N][256] bf16
             float* __restrict__ pml)          // [half*2+path][B*N][H][2]
{
    __shared__ float  biasL[4][16][66];   // [local h][q][m] f32 (log2e domain)
    __shared__ float  cds[16][68];        // [q][m] cd (log2e domain)
    __shared__ ushort ps[8][16][72];      // per-wave P (bf16)
    __shared__ float  w2Ls[4][4];         // local head weights (log2e-scaled)
    __shared__ float  b2Ls[4];

    const int n0 = blockIdx.x * 16;
    const int b  = blockIdx.y;
    const int hg   = blockIdx.z & 1;      // head group: heads hg*4 .. hg*4+3
    const int half = blockIdx.z >> 1;     // m-range half
    const size_t bN = (size_t)b * N_;
    const int tid = threadIdx.x;
    const int w = tid >> 6, lane = tid & 63;
    const int path = w >> 2, hl = w & 3;
    const int h = hg * 4 + hl;
    const int ql = lane & 15, g = lane >> 4;

    if (tid < 4) {
        b2Ls[tid] = sb_b2[hg * 4 + tid] * LOG2E_;
        #pragma unroll
        for (int i = 0; i < 4; ++i) w2Ls[tid][i] = sb_w2[(hg * 4 + tid) * 4 + i] * LOG2E_;
    }

    const float inv_bn = rsqrtf(1.0f + BN_EPS_);
    float w1s_[4], bnb_[4];
    #pragma unroll
    for (int i = 0; i < 4; ++i) {
        w1s_[i] = sb_w1[i] * sb_bn_g[i] * inv_bn;
        bnb_[i] = sb_bn_b[i];
    }

    // coop indices: 512 threads = 16 q x 32 m-pairs
    const int cq = tid >> 5, cm2 = tid & 31;
    const float ax = xyzA[(bN + n0 + cq) * 3 + 0];
    const float ay = xyzA[(bN + n0 + cq) * 3 + 1];
    const float az = xyzA[(bN + n0 + cq) * 3 + 2];

    bf16x8 qfrag = {};
    if (path == 0)
        qfrag = *(const bf16x8*)&q_bf[(bN + n0 + ql) * QLD_ + h * 32 + 8 * g];

    float m_i = -INFINITY, l_i = 0.f;
    f32x4 ctx0 = {0.f, 0.f, 0.f, 0.f};
    f32x4 ctx1 = {0.f, 0.f, 0.f, 0.f};
    const f32x4 zf = {0.f, 0.f, 0.f, 0.f};

    const int tBeg = half * (N_ / 128);          // 16 tiles per half
    const int tEnd = tBeg + (N_ / 128);

    for (int t = tBeg; t < tEnd; ++t) {
        const int m0 = t * 64;
        __syncthreads();   // prior tile's LDS reads done (also covers w2Ls init)

        // ---- coop: bias[4][16][64] f32 + cds ----
        {
            const int mA = m0 + 2 * cm2;
            const float* pb = xyzB + (bN + mA) * 3;
            float bx0 = pb[0], by0 = pb[1], bz0 = pb[2];
            float bx1 = pb[3], by1 = pb[4], bz1 = pb[5];
            float dx0 = ax - bx0, dy0 = ay - by0, dz0 = az - bz0;
            float dx1 = ax - bx1, dy1 = ay - by1, dz1 = az - bz1;
            float d0 = sqrtf(dx0 * dx0 + dy0 * dy0 + dz0 * dz0);
            float d1 = sqrtf(dx1 * dx1 + dy1 * dy1 + dz1 * dz1);
            float f0[4], f1[4];
            #pragma unroll
            for (int i = 0; i < 4; ++i) {
                f0[i] = fmaxf(fmaf(-w1s_[i], d0, bnb_[i]), 0.f);
                f1[i] = fmaxf(fmaf(-w1s_[i], d1, bnb_[i]), 0.f);
            }
            #pragma unroll
            for (int hh = 0; hh < 4; ++hh) {
                const f32x4 w2v = *(const f32x4*)w2Ls[hh];
                float b0 = b2Ls[hh], b1 = b2Ls[hh];
                #pragma unroll
                for (int i = 0; i < 4; ++i) {
                    b0 = fmaf(w2v[i], f0[i], b0);
                    b1 = fmaf(w2v[i], f1[i], b1);
                }
                *(float2*)&biasL[hh][cq][2 * cm2] = make_float2(b0, b1);
            }
            uint cv = *(const uint*)&cdb[(bN + n0 + cq) * (size_t)N_ + mA];
            cds[cq][2 * cm2]     = __uint_as_float(cv << 16);
            cds[cq][2 * cm2 + 1] = __uint_as_float(cv & 0xffff0000u);
        }
        __syncthreads();

        // ---- per-wave: issue global loads early ----
        bf16x8 af[4];
        if (path == 0) {
            #pragma unroll
            for (int mt = 0; mt < 4; ++mt)
                af[mt] = *(const bf16x8*)&k_bf[(bN + m0 + mt * 16 + ql) * QLD_ + h * 32 + 8 * g];
        }
        bf16x8 vb[2][2];
        #pragma unroll
        for (int kb = 0; kb < 2; ++kb)
            #pragma unroll
            for (int dt = 0; dt < 2; ++dt)
                vb[kb][dt] = *(const bf16x8*)&v_c[((size_t)b * C_ + h * 32 + dt * 16 + ql) * N_ + m0 + kb * 32 + 8 * g];

        // ---- s init from f32 bias LDS (aligned b64 pairs) ----
        float s[16];
        #pragma unroll
        for (int mt = 0; mt < 4; ++mt) {
            float2 blo = *(const float2*)&biasL[hl][ql][16 * mt + 4 * g];
            float2 bhi = *(const float2*)&biasL[hl][ql][16 * mt + 4 * g + 2];
            s[4 * mt + 0] = blo.x;
            s[4 * mt + 1] = blo.y;
            s[4 * mt + 2] = bhi.x;
            s[4 * mt + 3] = bhi.y;
        }

        if (path == 0) {
            #pragma unroll
            for (int mt = 0; mt < 4; ++mt) {
                f32x4 sf = __builtin_amdgcn_mfma_f32_16x16x32_bf16(af[mt], qfrag, zf, 0, 0, 0);
                #pragma unroll
                for (int r = 0; r < 4; ++r)
                    s[4 * mt + r] = fmaf(sf[r], ISDL_, s[4 * mt + r]);
            }
        } else {
            #pragma unroll
            for (int mt = 0; mt < 4; ++mt) {
                f32x4 cv = *(const f32x4*)&cds[ql][16 * mt + 4 * g];
                #pragma unroll
                for (int r = 0; r < 4; ++r)
                    s[4 * mt + r] += cv[r];
            }
        }

        // ---- online softmax with defer-max (pairwise max tree) ----
        float t0 = fmaxf(s[0], s[1]),   t1 = fmaxf(s[2], s[3]);
        float t2 = fmaxf(s[4], s[5]),   t3 = fmaxf(s[6], s[7]);
        float t4 = fmaxf(s[8], s[9]),   t5 = fmaxf(s[10], s[11]);
        float t6 = fmaxf(s[12], s[13]), t7 = fmaxf(s[14], s[15]);
        t0 = fmaxf(t0, t1); t2 = fmaxf(t2, t3);
        t4 = fmaxf(t4, t5); t6 = fmaxf(t6, t7);
        float tmax = fmaxf(fmaxf(t0, t2), fmaxf(t4, t6));
        tmax = fmaxf(tmax, __shfl_xor(tmax, 16));
        tmax = fmaxf(tmax, __shfl_xor(tmax, 32));
        if (!__all(tmax <= m_i + 8.0f)) {
            float mnew = fmaxf(m_i, tmax);
            float scl = exp2f(m_i - mnew);
            l_i *= scl;
            #pragma unroll
            for (int r = 0; r < 4; ++r) {
                float sr = lane_bcast(scl, 4 * g + r);
                ctx0[r] *= sr; ctx1[r] *= sr;
            }
            m_i = mnew;
        }
        float lsum = 0.f;
        #pragma unroll
        for (int j = 0; j < 16; ++j) {
            float pj = exp2f(s[j] - m_i);
            s[j] = pj;
            lsum += pj;
        }
        lsum += __shfl_xor(lsum, 16);
        lsum += __shfl_xor(lsum, 32);
        l_i += lsum;

        // ---- pack P -> per-wave LDS ----
        #pragma unroll
        for (int mt = 0; mt < 4; ++mt) {
            uint2 pk;
            pk.x = pack_bf2(s[4 * mt + 0], s[4 * mt + 1]);
            pk.y = pack_bf2(s[4 * mt + 2], s[4 * mt + 3]);
            *(uint2*)&ps[w][ql][16 * mt + 4 * g] = pk;
        }

        // ---- PV ----
        #pragma unroll
        for (int kb = 0; kb < 2; ++kb) {
            bf16x8 pa = *(const bf16x8*)&ps[w][ql][kb * 32 + 8 * g];
            ctx0 = __builtin_amdgcn_mfma_f32_16x16x32_bf16(pa, vb[kb][0], ctx0, 0, 0, 0);
            ctx1 = __builtin_amdgcn_mfma_f32_16x16x32_bf16(pa, vb[kb][1], ctx1, 0, 0, 0);
        }
    }

    // ---- epilogue: unnormalized partial ctx (bf16) + (m,l) ----
    const size_t sl = (size_t)(half * 2 + path) * (B_ * N_);
    #pragma unroll
    for (int r = 0; r < 4; ++r) {
        size_t base = (sl + bN + n0 + 4 * g + r) * C_ + h * 32;
        pc[base + ql]      = f2bf(ctx0[r]);
        pc[base + 16 + ql] = f2bf(ctx1[r]);
    }
    if (g == 0) {
        size_t mlb = ((sl + bN + n0 + ql) * H_ + h) * 2;
        pml[mlb]     = m_i;
        pml[mlb + 1] = l_i;
    }
}

// ---------------------------------------------------------------------------
// 5. merge halves + LayerNorm, write bf16 into fused_bf columns.
// ---------------------------------------------------------------------------
__global__ __launch_bounds__(256)
void k_merge_ln(const ushort* __restrict__ pc, const float* __restrict__ pml,
                const float* __restrict__ g_sim, const float* __restrict__ b_sim,
                const float* __restrict__ g_dis, const float* __restrict__ b_dis,
                ushort* __restrict__ fused_bf)
{
    __shared__ float rs_[4], rq_[4];
    const int row = blockIdx.x;           // global row in [0, B*N)
    const int path = blockIdx.y;
    const int c = threadIdx.x;
    const int h = c >> 5;
    const size_t i0 = (size_t)(0 * 2 + path) * (B_ * N_) + row;
    const size_t i1 = (size_t)(1 * 2 + path) * (B_ * N_) + row;
    const float m0 = pml[(i0 * H_ + h) * 2], l0 = pml[(i0 * H_ + h) * 2 + 1];
    const float m1 = pml[(i1 * H_ + h) * 2], l1 = pml[(i1 * H_ + h) * 2 + 1];
    const float M = fmaxf(m0, m1);
    const float w0 = exp2f(m0 - M), w1 = exp2f(m1 - M);
    const float il = 1.0f / fmaf(l0, w0, l1 * w1);
    const float v = fmaf(bf2f(pc[i0 * C_ + c]), w0, bf2f(pc[i1 * C_ + c]) * w1) * il;

    float s = v, q = v * v;
    #pragma unroll
    for (int off = 32; off; off >>= 1) { s += __shfl_xor(s, off); q += __shfl_xor(q, off); }
    const int wv = c >> 6, lane = c & 63;
    if (lane == 0) { rs_[wv] = s; rq_[wv] = q; }
    __syncthreads();
    float ss = rs_[0] + rs_[1] + rs_[2] + rs_[3];
    float qq = rq_[0] + rq_[1] + rq_[2] + rq_[3];
    float mean = ss * (1.0f / C_);
    float var  = qq * (1.0f / C_) - mean * mean;
    float rstd = rsqrtf(var + LN_EPS_);
    const float* gp = path ? g_dis : g_sim;
    const float* bp = path ? b_dis : b_sim;
    fused_bf[(size_t)row * (3 * C_) + C_ + path * C_ + c] =
        f2bf((v - mean) * rstd * gp[c] + bp[c]);
}

// ---------------------------------------------------------------------------
// 6. transpose [B*N,256] f32 -> [B,C,N] and add residual featA
// ---------------------------------------------------------------------------
__global__ __launch_bounds__(256)
void k_transpose_add(const float* __restrict__ fused_t,
                     const float* __restrict__ featA,
                     float* __restrict__ out)
{
    __shared__ float t[64][65];
    const int n0 = blockIdx.x * 64, c0 = blockIdx.y * 64, b = blockIdx.z;
    const int tid = threadIdx.x;
    #pragma unroll
    for (int i = 0; i < 16; ++i) {
        int e = i * 256 + tid;
        int nn = e >> 6, cc = e & 63;
        t[nn][cc] = fused_t[((size_t)b * N_ + n0 + nn) * C_ + c0 + cc];
    }
    __syncthreads();
    #pragma unroll
    for (int i = 0; i < 16; ++i) {
        int e = i * 256 + tid;
        int cc = e >> 6, nn = e & 63;
        size_t idx = ((size_t)b * C_ + c0 + cc) * N_ + n0 + nn;
        out[idx] = t[nn][cc] + featA[idx];
    }
}

// ---------------------------------------------------------------------------
extern "C" void kernel_launch(void* const* d_in, const int* in_sizes, int n_in,
                              void* d_out, int out_size, void* d_ws, size_t ws_size,
                              hipStream_t stream)
{
    const float* xyz_A   = (const float*)d_in[0];
    const float* featA   = (const float*)d_in[1];
    const float* xyz_B   = (const float*)d_in[2];
    const float* featB   = (const float*)d_in[3];
    const float* ln_in_g = (const float*)d_in[4];
    const float* ln_in_b = (const float*)d_in[5];
    const float* Wq  = (const float*)d_in[6];
    const float* bq  = (const float*)d_in[7];
    const float* Wk  = (const float*)d_in[8];
    const float* bk  = (const float*)d_in[9];
    const float* Wv  = (const float*)d_in[10];
    const float* bv  = (const float*)d_in[11];
    const float* sb_w1   = (const float*)d_in[12];
    const float* sb_bn_g = (const float*)d_in[13];
    const float* sb_bn_b = (const float*)d_in[14];
    const float* sb_w2   = (const float*)d_in[15];
    const float* sb_b2   = (const float*)d_in[16];
    const float* Wqd = (const float*)d_in[17];
    const float* bqd = (const float*)d_in[18];
    const float* Wkd = (const float*)d_in[19];
    const float* bkd = (const float*)d_in[20];
    const float* ln_sim_g = (const float*)d_in[21];
    const float* ln_sim_b = (const float*)d_in[22];
    const float* ln_dis_g = (const float*)d_in[23];
    const float* ln_dis_b = (const float*)d_in[24];
    const float* Wf1   = (const float*)d_in[25];
    const float* bnf_g = (const float*)d_in[26];
    const float* bnf_b = (const float*)d_in[27];
    const float* Wf2   = (const float*)d_in[28];
    const float* bf2   = (const float*)d_in[29];
    float* out = (float*)d_out;

    float* ws = (float*)d_ws;
    size_t off = 0;
    auto alloc = [&](size_t n) { float* p = ws + off; off += n; return p; };
    const size_t RN = (size_t)B_ * N_;   // 4096 rows

    ushort* fused_bf = (ushort*)alloc(RN * 384);       // [RN][768] bf16
    ushort* featB_bf = (ushort*)alloc(RN * 128);       // [RN][256] bf16
    ushort* qqd_bf   = (ushort*)alloc(RN * 256);       // [RN][512] bf16 (q|qd)
    ushort* kkd_bf   = (ushort*)alloc(RN * 256);       // [RN][512] bf16 (k|kd)
    ushort* v_bf     = (ushort*)alloc(RN * 128);       // [B][256][N] bf16
    ushort* wbf      = (ushort*)alloc(425984);         // 851968 bf16 weights
    float*  bqqd     = alloc(512);
    float*  bkkd     = alloc(512);
    float*  qn       = alloc(RN);
    float*  kn       = alloc(RN);
    ushort* cd_bf    = (ushort*)alloc((size_t)B_ * N_ * N_ / 2); // bf16; reused fh+fused_t
    ushort* pc       = (ushort*)alloc(4 * RN * C_ / 2);// [4][RN][256] bf16 partial ctx
    float*  pml      = alloc(4 * RN * H_ * 2);         // [4][RN][H][2]

    ushort* q_bf  = qqd_bf;            // stride 512, cols 0..255
    ushort* qd_bf = qqd_bf + 256;      // stride 512
    ushort* k_bf  = kkd_bf;
    ushort* kd_bf = kkd_bf + 256;
    ushort* fh      = cd_bf;                            // [RN][512] bf16 (cd dead after attn)
    float*  fused_t = (float*)(cd_bf + (size_t)RN * 512); // f32 [RN][256]

    ushort* wqqd_bf = wbf;             // [512][256]
    ushort* wkkd_bf = wbf + 131072;    // [512][256]
    ushort* wv_bf   = wbf + 262144;
    ushort* wf1_bf  = wbf + 327680;
    ushort* wf2_bf  = wbf + 720896;
    (void)ws_size; (void)in_sizes; (void)n_in; (void)out_size;

    dim3 blk(256);

    // 0) weights -> bf16 ; biases concat ; 1) LN/transpose -> bf16
    k_wconv<<<dim3(416), blk, 0, stream>>>(Wq, Wqd, Wk, Wkd, Wv, Wf1, Wf2, wbf);
    k_bconcat<<<dim3(1), dim3(512), 0, stream>>>(bq, bqd, bk, bkd, bqqd, bkkd);
    k_ln_transpose<true ><<<dim3(B_ * (N_ / 64)), blk, 0, stream>>>(featA, ln_in_g, ln_in_b, fused_bf, 3 * C_);
    k_ln_transpose<false><<<dim3(B_ * (N_ / 64)), blk, 0, stream>>>(featB, nullptr, nullptr, featB_bf, C_);

    // 2) fused projections (R8 config: 64^2 everywhere): q|qd, k|kd, v^T
    k_gemm_bf<0,1><<<dim3(RN / 64, 8, 1), blk, 0, stream>>>(fused_bf, 3 * C_, 0, wqqd_bf, C_, 0, qqd_bf, 512, 0, C_, bqqd, nullptr);
    k_gemm_bf<0,1><<<dim3(RN / 64, 8, 1), blk, 0, stream>>>(featB_bf, C_,     0, wkkd_bf, C_, 0, kkd_bf, 512, 0, C_, bkkd, nullptr);
    k_gemm_bf<3,1><<<dim3(C_ / 64, N_ / 64, B_), blk, 0, stream>>>(wv_bf, C_, 0, featB_bf, C_, (size_t)N_ * C_, v_bf, N_, (size_t)C_ * N_, C_, bv, nullptr);

    // 3) feature-cdist (bf16 out, log2e-domain)
    k_rownorm<<<dim3(RN / 4), blk, 0, stream>>>(qd_bf, 512, qn);
    k_rownorm<<<dim3(RN / 4), blk, 0, stream>>>(kd_bf, 512, kn);
    k_gemm_bf<1,1><<<dim3(N_ / 64, N_ / 64, B_), blk, 0, stream>>>(qd_bf, 512, (size_t)N_ * 512,
                                                                   kd_bf, 512, (size_t)N_ * 512,
                                                                   cd_bf, N_, (size_t)N_ * N_, C_, qn, kn);

    // 4) fused attention v6 (split-m + split-head) + fused merge+LN
    k_attn6<<<dim3(N_ / 16, B_, 4), dim3(512), 0, stream>>>(q_bf, k_bf, v_bf, xyz_A, xyz_B, cd_bf,
                                                            sb_w1, sb_bn_g, sb_bn_b, sb_w2, sb_b2,
                                                            pc, pml);
    k_merge_ln<<<dim3(RN, 2), blk, 0, stream>>>(pc, pml, ln_sim_g, ln_sim_b, ln_dis_g, ln_dis_b, fused_bf);

    // 5) fused MLP: Wf1, Wf2 (64^2, R8 config)
    k_gemm_bf<2,1><<<dim3(RN / 64, 8, 1), blk, 0, stream>>>(fused_bf, 3 * C_, 0, wf1_bf, 3 * C_, 0, fh, 2 * C_, 0, 3 * C_, bnf_g, bnf_b);
    k_gemm_bf<0,0><<<dim3(RN / 64, 4, 1), blk, 0, stream>>>(fh, 2 * C_, 0, wf2_bf, 2 * C_, 0, fused_t, C_, 0, 2 * C_, bf2, nullptr);

    // 6) transpose + residual
    k_transpose_add<<<dim3(N_ / 64, C_ / 64, B_), blk, 0, stream>>>(fused_t, featA, out);
}

// Round 13
// 204.408 us; speedup vs baseline: 1.0892x; 1.0151x over previous
//
#include <hip/hip_runtime.h>
#include <math.h>

#define B_ 2
#define N_ 2048
#define C_ 256
#define H_ 8
#define HD_ 32
constexpr float LN_EPS_ = 1e-5f;
constexpr float BN_EPS_ = 1e-5f;
constexpr float LOG2E_ = 1.4426950408889634f;
constexpr float ISDL_ = 0.17677669529663687f * 1.4426950408889634f; // 1/sqrt(32)*log2e

typedef __attribute__((ext_vector_type(8))) short bf16x8;
typedef __attribute__((ext_vector_type(4))) float f32x4;

static __device__ inline ushort f2bf(float x) {
    union { float f; uint u; } c{x};
    uint r = (c.u + 0x7FFF + ((c.u >> 16) & 1)) >> 16;
    return (ushort)r;
}
static __device__ inline float bf2f(ushort u) {
    union { uint i; float f; } c; c.i = ((uint)u) << 16; return c.f;
}
static __device__ inline float bf_lo(uint u) { return __uint_as_float(u << 16); }
static __device__ inline float bf_hi(uint u) { return __uint_as_float(u & 0xffff0000u); }
static __device__ inline float lane_bcast(float v, int srclane) {
    return __int_as_float(__builtin_amdgcn_ds_bpermute(srclane * 4, __float_as_int(v)));
}
// pack two f32 -> two bf16 (round-half-up): low16 = bf16(lo), high16 = bf16(hi)
static __device__ inline uint pack_bf2(float lo, float hi) {
    uint ul = __float_as_uint(lo) + 0x8000u;
    uint uh = __float_as_uint(hi) + 0x8000u;
    return __builtin_amdgcn_perm(uh, ul, 0x07060302u);
}

// ---------------------------------------------------------------------------
// 0. weight conversion f32 -> bf16. Layout (elements):
//    wq(0) wqd(65536) wk(131072) wkd(196608) wv(262144) wf1(327680) wf2(720896)
// ---------------------------------------------------------------------------
__global__ __launch_bounds__(256)
void k_wconv(const float* __restrict__ Wq, const float* __restrict__ Wqd,
             const float* __restrict__ Wk, const float* __restrict__ Wkd,
             const float* __restrict__ Wv, const float* __restrict__ Wf1,
             const float* __restrict__ Wf2, ushort* __restrict__ dst)
{
    size_t e0 = ((size_t)blockIdx.x * 256 + threadIdx.x) * 8;
    const float* src = Wq; size_t base = 0;
    if (e0 >= 65536)  { src = Wqd; base = 65536; }
    if (e0 >= 131072) { src = Wk;  base = 131072; }
    if (e0 >= 196608) { src = Wkd; base = 196608; }
    if (e0 >= 262144) { src = Wv;  base = 262144; }
    if (e0 >= 327680) { src = Wf1; base = 327680; }
    if (e0 >= 720896) { src = Wf2; base = 720896; }
    float4 a = *(const float4*)(src + (e0 - base));
    float4 b = *(const float4*)(src + (e0 - base) + 4);
    ushort o[8] = {f2bf(a.x), f2bf(a.y), f2bf(a.z), f2bf(a.w),
                   f2bf(b.x), f2bf(b.y), f2bf(b.z), f2bf(b.w)};
    *(uint4*)(dst + e0) = *(uint4*)o;
}

// 0b. bias concat for fused projections
__global__ __launch_bounds__(512)
void k_bconcat(const float* __restrict__ bq, const float* __restrict__ bqd,
               const float* __restrict__ bk, const float* __restrict__ bkd,
               float* __restrict__ bqqd, float* __restrict__ bkkd)
{
    int t = threadIdx.x;
    bqqd[t] = (t < 256) ? bq[t] : bqd[t - 256];
    bkkd[t] = (t < 256) ? bk[t] : bkd[t - 256];
}

// ---------------------------------------------------------------------------
// 1. LN-over-C with transpose: in [B,C,N] f32 -> bf16 rows [(b*N+n)*ld + c]
// ---------------------------------------------------------------------------
template<bool DO_LN>
__global__ __launch_bounds__(256)
void k_ln_transpose(const float* __restrict__ x,
                    const float* __restrict__ g,
                    const float* __restrict__ bt,
                    ushort* __restrict__ out, int ld)
{
    __shared__ float tile[C_][65];
    __shared__ float red_s[4][64];
    __shared__ float red_q[4][64];
    __shared__ float ms[64];
    __shared__ float rs[64];

    const int b  = blockIdx.x / (N_ / 64);
    const int n0 = (blockIdx.x % (N_ / 64)) * 64;
    const int tid = threadIdx.x;

    for (int i = 0; i < 64; ++i) {
        int c = i * 4 + (tid >> 6);
        int n = tid & 63;
        tile[c][n] = x[((size_t)b * C_ + c) * N_ + n0 + n];
    }
    __syncthreads();

    float gv = 0.f, bv = 0.f;
    if (DO_LN) { gv = g[tid]; bv = bt[tid]; }

    if (DO_LN) {
        const int nl = tid & 63, part = tid >> 6;
        float s = 0.f, q = 0.f;
        for (int j = 0; j < 64; ++j) {
            float v = tile[part * 64 + j][nl];
            s += v; q += v * v;
        }
        red_s[part][nl] = s; red_q[part][nl] = q;
        __syncthreads();
        if (tid < 64) {
            float ss = red_s[0][tid] + red_s[1][tid] + red_s[2][tid] + red_s[3][tid];
            float qq = red_q[0][tid] + red_q[1][tid] + red_q[2][tid] + red_q[3][tid];
            float mean = ss * (1.0f / C_);
            float var  = qq * (1.0f / C_) - mean * mean;
            ms[tid] = mean;
            rs[tid] = rsqrtf(var + LN_EPS_);
        }
        __syncthreads();
    }

    for (int i = 0; i < 64; ++i) {
        float v = tile[tid][i];
        if (DO_LN) v = (v - ms[i]) * rs[i] * gv + bv;
        out[((size_t)b * N_ + n0 + i) * ld + tid] = f2bf(v);
    }
}

// ---------------------------------------------------------------------------
// 2. MFMA NT GEMM, 64x64 tile, 4 waves, BK=32 (the R8-proven config).
//    EPI 0:+aux1[col]; 1: cdist sqrt * LOG2E; 2: BN+relu; 3:+aux1[row].
//    OUT 0: f32 store; 1: bf16 store.
// ---------------------------------------------------------------------------
template<int EPI, int OUT>
__global__ __launch_bounds__(256)
void k_gemm_bf(const ushort* __restrict__ A, int lda, size_t sAz,
               const ushort* __restrict__ Bw, int ldb, size_t sBz,
               void* __restrict__ Cout_, int ldc, size_t sCz,
               int K,
               const float* __restrict__ aux1,
               const float* __restrict__ aux2)
{
    const int z = blockIdx.z;
    A  += (size_t)z * sAz;
    Bw += (size_t)z * sBz;

    const int r0 = blockIdx.x * 64;
    const int c0 = blockIdx.y * 64;
    const int tid = threadIdx.x;
    const int w = tid >> 6, lane = tid & 63;
    const int wr = w >> 1, wc = w & 1;
    const int ql = lane & 15, g = lane >> 4;

    __shared__ ushort As[64][40];
    __shared__ ushort Bs[64][40];

    f32x4 acc[2][2] = {};
    const int srow = tid >> 2;
    const int sk   = (tid & 3) * 8;

    for (int k0 = 0; k0 < K; k0 += 32) {
        bf16x8 av = *(const bf16x8*)&A[(size_t)(r0 + srow) * lda + k0 + sk];
        bf16x8 bv = *(const bf16x8*)&Bw[(size_t)(c0 + srow) * ldb + k0 + sk];
        __syncthreads();
        *(bf16x8*)&As[srow][sk] = av;
        *(bf16x8*)&Bs[srow][sk] = bv;
        __syncthreads();
        bf16x8 af[2], bf[2];
        #pragma unroll
        for (int i = 0; i < 2; ++i) {
            af[i] = *(const bf16x8*)&As[wr * 32 + i * 16 + ql][8 * g];
            bf[i] = *(const bf16x8*)&Bs[wc * 32 + i * 16 + ql][8 * g];
        }
        #pragma unroll
        for (int mi = 0; mi < 2; ++mi)
            #pragma unroll
            for (int ni = 0; ni < 2; ++ni)
                acc[mi][ni] = __builtin_amdgcn_mfma_f32_16x16x32_bf16(af[mi], bf[ni], acc[mi][ni], 0, 0, 0);
    }

    const float inv_bn = rsqrtf(1.0f + BN_EPS_);
    float*  Cf = (float*)Cout_  + (size_t)z * sCz;
    ushort* Cb = (ushort*)Cout_ + (size_t)z * sCz;
    #pragma unroll
    for (int mi = 0; mi < 2; ++mi) {
        #pragma unroll
        for (int ni = 0; ni < 2; ++ni) {
            #pragma unroll
            for (int r = 0; r < 4; ++r) {
                int row = r0 + wr * 32 + mi * 16 + 4 * g + r;
                int col = c0 + wc * 32 + ni * 16 + ql;
                float v = acc[mi][ni][r];
                if (EPI == 0) {
                    v += aux1[col];
                } else if (EPI == 1) {
                    float qnv = aux1[(size_t)z * N_ + row];
                    float knv = aux2[(size_t)z * N_ + col];
                    v = sqrtf(fmaxf(qnv + knv - 2.0f * v, 0.f)) * LOG2E_;
                } else if (EPI == 2) {
                    v = fmaxf(v * (aux1[col] * inv_bn) + aux2[col], 0.f);
                } else if (EPI == 3) {
                    v += aux1[row];
                }
                if (OUT == 0) Cf[(size_t)row * ldc + col] = v;
                else          Cb[(size_t)row * ldc + col] = f2bf(v);
            }
        }
    }
}

// ---------------------------------------------------------------------------
// 3. row squared-norm over bf16 rows [R,256] with row stride ld
// ---------------------------------------------------------------------------
__global__ __launch_bounds__(256)
void k_rownorm(const ushort* __restrict__ x, int ld, float* __restrict__ outn)
{
    const int r = blockIdx.x * 4 + (threadIdx.x >> 6);
    const int lane = threadIdx.x & 63;
    uint2 pv = *(const uint2*)&x[(size_t)r * ld + lane * 4];
    float v0 = bf2f((ushort)(pv.x & 0xffff)), v1 = bf2f((ushort)(pv.x >> 16));
    float v2 = bf2f((ushort)(pv.y & 0xffff)), v3 = bf2f((ushort)(pv.y >> 16));
    float s = v0 * v0 + v1 * v1 + v2 * v2 + v3 * v3;
    #pragma unroll
    for (int off = 32; off; off >>= 1) s += __shfl_xor(s, off);
    if (lane == 0) outn[r] = s;
}

// ---------------------------------------------------------------------------
// 4. fused attention v7: split-m + split-head; SINGLE barrier per tile via
//    double-buffered coop LDS (bf16) + async-stage register prefetch (T14);
//    s_setprio around MFMA clusters (T5).
//    512 thr = 8 waves = (2 paths x 4 heads). grid (N/16, B, 2 half x 2 hg).
// ---------------------------------------------------------------------------
#define QLD_ 512
__global__ __launch_bounds__(512, 4)
void k_attn7(const ushort* __restrict__ q_bf,  // [B*N][512] (cols 0..255 = q)
             const ushort* __restrict__ k_bf,  // [B*N][512] (cols 0..255 = k)
             const ushort* __restrict__ v_c,   // [B][256][N]
             const float* __restrict__ xyzA,   // [B][N][3]
             const float* __restrict__ xyzB,   // [B][N][3]
             const ushort* __restrict__ cdb,   // [B][N][N] bf16, log2e-domain
             const float* __restrict__ sb_w1, const float* __restrict__ sb_bn_g,
             const float* __restrict__ sb_bn_b, const float* __restrict__ sb_w2,
             const float* __restrict__ sb_b2,
             ushort* __restrict__ pc,          // [half*2+path][B*N][256] bf16
             float* __restrict__ pml)          // [half*2+path][B*N][H][2]
{
    __shared__ ushort biasL[2][4][16][72]; // bf16 bias, double-buffered (log2e dom.)
    __shared__ ushort cdsL[2][16][72];     // bf16 cd (log2e domain), double-buffered
    __shared__ ushort ps[8][16][72];       // per-wave P (bf16)
    __shared__ float  w2Ls[4][4];
    __shared__ float  b2Ls[4];

    const int n0 = blockIdx.x * 16;
    const int b  = blockIdx.y;
    const int hg   = blockIdx.z & 1;
    const int half = blockIdx.z >> 1;
    const size_t bN = (size_t)b * N_;
    const int tid = threadIdx.x;
    const int w = tid >> 6, lane = tid & 63;
    const int path = w >> 2, hl = w & 3;
    const int h = hg * 4 + hl;
    const int ql = lane & 15, g = lane >> 4;

    if (tid < 4) {
        b2Ls[tid] = sb_b2[hg * 4 + tid] * LOG2E_;
        #pragma unroll
        for (int i = 0; i < 4; ++i) w2Ls[tid][i] = sb_w2[(hg * 4 + tid) * 4 + i] * LOG2E_;
    }

    const float inv_bn = rsqrtf(1.0f + BN_EPS_);
    float w1s_[4], bnb_[4];
    #pragma unroll
    for (int i = 0; i < 4; ++i) {
        w1s_[i] = sb_w1[i] * sb_bn_g[i] * inv_bn;
        bnb_[i] = sb_bn_b[i];
    }

    // coop indices: 512 threads = 16 q x 32 m-pairs
    const int cq = tid >> 5, cm2 = tid & 31;
    const float ax = xyzA[(bN + n0 + cq) * 3 + 0];
    const float ay = xyzA[(bN + n0 + cq) * 3 + 1];
    const float az = xyzA[(bN + n0 + cq) * 3 + 2];

    bf16x8 qfrag = {};
    if (path == 0)
        qfrag = *(const bf16x8*)&q_bf[(bN + n0 + ql) * QLD_ + h * 32 + 8 * g];

    float m_i = -INFINITY, l_i = 0.f;
    f32x4 ctx0 = {0.f, 0.f, 0.f, 0.f};
    f32x4 ctx1 = {0.f, 0.f, 0.f, 0.f};
    const f32x4 zf = {0.f, 0.f, 0.f, 0.f};

    const int tBeg = half * (N_ / 128);
    const int tEnd = tBeg + (N_ / 128);

    // prefetch registers for coop stage (T14 async split)
    float xb[6]; uint cdv;
    auto coop_load = [&](int t) {
        const int mA = t * 64 + 2 * cm2;
        const float* pb = xyzB + (bN + mA) * 3;
        #pragma unroll
        for (int i = 0; i < 6; ++i) xb[i] = pb[i];
        cdv = *(const uint*)&cdb[(bN + n0 + cq) * (size_t)N_ + mA];
    };
    auto coop_write = [&](int buf) {
        float dx0 = ax - xb[0], dy0 = ay - xb[1], dz0 = az - xb[2];
        float dx1 = ax - xb[3], dy1 = ay - xb[4], dz1 = az - xb[5];
        float d0 = sqrtf(dx0 * dx0 + dy0 * dy0 + dz0 * dz0);
        float d1 = sqrtf(dx1 * dx1 + dy1 * dy1 + dz1 * dz1);
        float f0[4], f1[4];
        #pragma unroll
        for (int i = 0; i < 4; ++i) {
            f0[i] = fmaxf(fmaf(-w1s_[i], d0, bnb_[i]), 0.f);
            f1[i] = fmaxf(fmaf(-w1s_[i], d1, bnb_[i]), 0.f);
        }
        #pragma unroll
        for (int hh = 0; hh < 4; ++hh) {
            const f32x4 w2v = *(const f32x4*)w2Ls[hh];
            float b0 = b2Ls[hh], b1 = b2Ls[hh];
            #pragma unroll
            for (int i = 0; i < 4; ++i) {
                b0 = fmaf(w2v[i], f0[i], b0);
                b1 = fmaf(w2v[i], f1[i], b1);
            }
            *(uint*)&biasL[buf][hh][cq][2 * cm2] = pack_bf2(b0, b1);
        }
        *(uint*)&cdsL[buf][cq][2 * cm2] = cdv;
    };

    // prologue: fill buf 0 (w2Ls init is visible after the first barrier is
    // not needed here: coop_write reads w2Ls — so do a tiny sync first)
    __syncthreads();              // w2Ls/b2Ls ready
    coop_load(tBeg);
    coop_write(0);
    if (tBeg + 1 < tEnd) coop_load(tBeg + 1);
    __syncthreads();              // buf0 ready

    for (int t = tBeg; t < tEnd; ++t) {
        const int cur = (t - tBeg) & 1;

        // coop for tile t+1 (regs already loaded); then prefetch t+2
        if (t + 1 < tEnd) {
            coop_write(cur ^ 1);
            if (t + 2 < tEnd) coop_load(t + 2);
        }

        // ---- per-wave: issue global loads early ----
        const int m0 = t * 64;
        bf16x8 af[4];
        if (path == 0) {
            #pragma unroll
            for (int mt = 0; mt < 4; ++mt)
                af[mt] = *(const bf16x8*)&k_bf[(bN + m0 + mt * 16 + ql) * QLD_ + h * 32 + 8 * g];
        }
        bf16x8 vb[2][2];
        #pragma unroll
        for (int kb = 0; kb < 2; ++kb)
            #pragma unroll
            for (int dt = 0; dt < 2; ++dt)
                vb[kb][dt] = *(const bf16x8*)&v_c[((size_t)b * C_ + h * 32 + dt * 16 + ql) * N_ + m0 + kb * 32 + 8 * g];

        // ---- s init from bf16 bias (+cd for dis path) ----
        float s[16];
        #pragma unroll
        for (int mt = 0; mt < 4; ++mt) {
            uint2 bw = *(const uint2*)&biasL[cur][hl][ql][16 * mt + 4 * g];
            s[4 * mt + 0] = bf_lo(bw.x);
            s[4 * mt + 1] = bf_hi(bw.x);
            s[4 * mt + 2] = bf_lo(bw.y);
            s[4 * mt + 3] = bf_hi(bw.y);
        }

        if (path == 0) {
            __builtin_amdgcn_s_setprio(1);
            #pragma unroll
            for (int mt = 0; mt < 4; ++mt) {
                f32x4 sf = __builtin_amdgcn_mfma_f32_16x16x32_bf16(af[mt], qfrag, zf, 0, 0, 0);
                #pragma unroll
                for (int r = 0; r < 4; ++r)
                    s[4 * mt + r] = fmaf(sf[r], ISDL_, s[4 * mt + r]);
            }
            __builtin_amdgcn_s_setprio(0);
        } else {
            #pragma unroll
            for (int mt = 0; mt < 4; ++mt) {
                uint2 cw = *(const uint2*)&cdsL[cur][ql][16 * mt + 4 * g];
                s[4 * mt + 0] += bf_lo(cw.x);
                s[4 * mt + 1] += bf_hi(cw.x);
                s[4 * mt + 2] += bf_lo(cw.y);
                s[4 * mt + 3] += bf_hi(cw.y);
            }
        }

        // ---- online softmax with defer-max (pairwise max tree) ----
        float t0 = fmaxf(s[0], s[1]),   t1 = fmaxf(s[2], s[3]);
        float t2 = fmaxf(s[4], s[5]),   t3 = fmaxf(s[6], s[7]);
        float t4 = fmaxf(s[8], s[9]),   t5 = fmaxf(s[10], s[11]);
        float t6 = fmaxf(s[12], s[13]), t7 = fmaxf(s[14], s[15]);
        t0 = fmaxf(t0, t1); t2 = fmaxf(t2, t3);
        t4 = fmaxf(t4, t5); t6 = fmaxf(t6, t7);
        float tmax = fmaxf(fmaxf(t0, t2), fmaxf(t4, t6));
        tmax = fmaxf(tmax, __shfl_xor(tmax, 16));
        tmax = fmaxf(tmax, __shfl_xor(tmax, 32));
        if (!__all(tmax <= m_i + 8.0f)) {
            float mnew = fmaxf(m_i, tmax);
            float scl = exp2f(m_i - mnew);
            l_i *= scl;
            #pragma unroll
            for (int r = 0; r < 4; ++r) {
                float sr = lane_bcast(scl, 4 * g + r);
                ctx0[r] *= sr; ctx1[r] *= sr;
            }
            m_i = mnew;
        }
        float lsum = 0.f;
        #pragma unroll
        for (int j = 0; j < 16; ++j) {
            float pj = exp2f(s[j] - m_i);
            s[j] = pj;
            lsum += pj;
        }
        lsum += __shfl_xor(lsum, 16);
        lsum += __shfl_xor(lsum, 32);
        l_i += lsum;

        // ---- pack P -> per-wave LDS ----
        #pragma unroll
        for (int mt = 0; mt < 4; ++mt) {
            uint2 pk;
            pk.x = pack_bf2(s[4 * mt + 0], s[4 * mt + 1]);
            pk.y = pack_bf2(s[4 * mt + 2], s[4 * mt + 3]);
            *(uint2*)&ps[w][ql][16 * mt + 4 * g] = pk;
        }

        // ---- PV ----
        __builtin_amdgcn_s_setprio(1);
        #pragma unroll
        for (int kb = 0; kb < 2; ++kb) {
            bf16x8 pa = *(const bf16x8*)&ps[w][ql][kb * 32 + 8 * g];
            ctx0 = __builtin_amdgcn_mfma_f32_16x16x32_bf16(pa, vb[kb][0], ctx0, 0, 0, 0);
            ctx1 = __builtin_amdgcn_mfma_f32_16x16x32_bf16(pa, vb[kb][1], ctx1, 0, 0, 0);
        }
        __builtin_amdgcn_s_setprio(0);

        __syncthreads();   // buf[cur^1] written + buf[cur] reads done
    }

    // ---- epilogue: unnormalized partial ctx (bf16) + (m,l) ----
    const size_t sl = (size_t)(half * 2 + path) * (B_ * N_);
    #pragma unroll
    for (int r = 0; r < 4; ++r) {
        size_t base = (sl + bN + n0 + 4 * g + r) * C_ + h * 32;
        pc[base + ql]      = f2bf(ctx0[r]);
        pc[base + 16 + ql] = f2bf(ctx1[r]);
    }
    if (g == 0) {
        size_t mlb = ((sl + bN + n0 + ql) * H_ + h) * 2;
        pml[mlb]     = m_i;
        pml[mlb + 1] = l_i;
    }
}

// ---------------------------------------------------------------------------
// 5. merge halves + LayerNorm, write bf16 into fused_bf columns.
// ---------------------------------------------------------------------------
__global__ __launch_bounds__(256)
void k_merge_ln(const ushort* __restrict__ pc, const float* __restrict__ pml,
                const float* __restrict__ g_sim, const float* __restrict__ b_sim,
                const float* __restrict__ g_dis, const float* __restrict__ b_dis,
                ushort* __restrict__ fused_bf)
{
    __shared__ float rs_[4], rq_[4];
    const int row = blockIdx.x;           // global row in [0, B*N)
    const int path = blockIdx.y;
    const int c = threadIdx.x;
    const int h = c >> 5;
    const size_t i0 = (size_t)(0 * 2 + path) * (B_ * N_) + row;
    const size_t i1 = (size_t)(1 * 2 + path) * (B_ * N_) + row;
    const float m0 = pml[(i0 * H_ + h) * 2], l0 = pml[(i0 * H_ + h) * 2 + 1];
    const float m1 = pml[(i1 * H_ + h) * 2], l1 = pml[(i1 * H_ + h) * 2 + 1];
    const float M = fmaxf(m0, m1);
    const float w0 = exp2f(m0 - M), w1 = exp2f(m1 - M);
    const float il = 1.0f / fmaf(l0, w0, l1 * w1);
    const float v = fmaf(bf2f(pc[i0 * C_ + c]), w0, bf2f(pc[i1 * C_ + c]) * w1) * il;

    float s = v, q = v * v;
    #pragma unroll
    for (int off = 32; off; off >>= 1) { s += __shfl_xor(s, off); q += __shfl_xor(q, off); }
    const int wv = c >> 6, lane = c & 63;
    if (lane == 0) { rs_[wv] = s; rq_[wv] = q; }
    __syncthreads();
    float ss = rs_[0] + rs_[1] + rs_[2] + rs_[3];
    float qq = rq_[0] + rq_[1] + rq_[2] + rq_[3];
    float mean = ss * (1.0f / C_);
    float var  = qq * (1.0f / C_) - mean * mean;
    float rstd = rsqrtf(var + LN_EPS_);
    const float* gp = path ? g_dis : g_sim;
    const float* bp = path ? b_dis : b_sim;
    fused_bf[(size_t)row * (3 * C_) + C_ + path * C_ + c] =
        f2bf((v - mean) * rstd * gp[c] + bp[c]);
}

// ---------------------------------------------------------------------------
// 6. transpose [B*N,256] f32 -> [B,C,N] and add residual featA
// ---------------------------------------------------------------------------
__global__ __launch_bounds__(256)
void k_transpose_add(const float* __restrict__ fused_t,
                     const float* __restrict__ featA,
                     float* __restrict__ out)
{
    __shared__ float t[64][65];
    const int n0 = blockIdx.x * 64, c0 = blockIdx.y * 64, b = blockIdx.z;
    const int tid = threadIdx.x;
    #pragma unroll
    for (int i = 0; i < 16; ++i) {
        int e = i * 256 + tid;
        int nn = e >> 6, cc = e & 63;
        t[nn][cc] = fused_t[((size_t)b * N_ + n0 + nn) * C_ + c0 + cc];
    }
    __syncthreads();
    #pragma unroll
    for (int i = 0; i < 16; ++i) {
        int e = i * 256 + tid;
        int cc = e >> 6, nn = e & 63;
        size_t idx = ((size_t)b * C_ + c0 + cc) * N_ + n0 + nn;
        out[idx] = t[nn][cc] + featA[idx];
    }
}

// ---------------------------------------------------------------------------
extern "C" void kernel_launch(void* const* d_in, const int* in_sizes, int n_in,
                              void* d_out, int out_size, void* d_ws, size_t ws_size,
                              hipStream_t stream)
{
    const float* xyz_A   = (const float*)d_in[0];
    const float* featA   = (const float*)d_in[1];
    const float* xyz_B   = (const float*)d_in[2];
    const float* featB   = (const float*)d_in[3];
    const float* ln_in_g = (const float*)d_in[4];
    const float* ln_in_b = (const float*)d_in[5];
    const float* Wq  = (const float*)d_in[6];
    const float* bq  = (const float*)d_in[7];
    const float* Wk  = (const float*)d_in[8];
    const float* bk  = (const float*)d_in[9];
    const float* Wv  = (const float*)d_in[10];
    const float* bv  = (const float*)d_in[11];
    const float* sb_w1   = (const float*)d_in[12];
    const float* sb_bn_g = (const float*)d_in[13];
    const float* sb_bn_b = (const float*)d_in[14];
    const float* sb_w2   = (const float*)d_in[15];
    const float* sb_b2   = (const float*)d_in[16];
    const float* Wqd = (const float*)d_in[17];
    const float* bqd = (const float*)d_in[18];
    const float* Wkd = (const float*)d_in[19];
    const float* bkd = (const float*)d_in[20];
    const float* ln_sim_g = (const float*)d_in[21];
    const float* ln_sim_b = (const float*)d_in[22];
    const float* ln_dis_g = (const float*)d_in[23];
    const float* ln_dis_b = (const float*)d_in[24];
    const float* Wf1   = (const float*)d_in[25];
    const float* bnf_g = (const float*)d_in[26];
    const float* bnf_b = (const float*)d_in[27];
    const float* Wf2   = (const float*)d_in[28];
    const float* bf2   = (const float*)d_in[29];
    float* out = (float*)d_out;

    float* ws = (float*)d_ws;
    size_t off = 0;
    auto alloc = [&](size_t n) { float* p = ws + off; off += n; return p; };
    const size_t RN = (size_t)B_ * N_;   // 4096 rows

    ushort* fused_bf = (ushort*)alloc(RN * 384);       // [RN][768] bf16
    ushort* featB_bf = (ushort*)alloc(RN * 128);       // [RN][256] bf16
    ushort* qqd_bf   = (ushort*)alloc(RN * 256);       // [RN][512] bf16 (q|qd)
    ushort* kkd_bf   = (ushort*)alloc(RN * 256);       // [RN][512] bf16 (k|kd)
    ushort* v_bf     = (ushort*)alloc(RN * 128);       // [B][256][N] bf16
    ushort* wbf      = (ushort*)alloc(425984);         // 851968 bf16 weights
    float*  bqqd     = alloc(512);
    float*  bkkd     = alloc(512);
    float*  qn       = alloc(RN);
    float*  kn       = alloc(RN);
    ushort* cd_bf    = (ushort*)alloc((size_t)B_ * N_ * N_ / 2); // bf16; reused fh+fused_t
    ushort* pc       = (ushort*)alloc(4 * RN * C_ / 2);// [4][RN][256] bf16 partial ctx
    float*  pml      = alloc(4 * RN * H_ * 2);         // [4][RN][H][2]

    ushort* q_bf  = qqd_bf;            // stride 512, cols 0..255
    ushort* qd_bf = qqd_bf + 256;      // stride 512
    ushort* k_bf  = kkd_bf;
    ushort* kd_bf = kkd_bf + 256;
    ushort* fh      = cd_bf;                            // [RN][512] bf16 (cd dead after attn)
    float*  fused_t = (float*)(cd_bf + (size_t)RN * 512); // f32 [RN][256]

    ushort* wqqd_bf = wbf;             // [512][256]
    ushort* wkkd_bf = wbf + 131072;    // [512][256]
    ushort* wv_bf   = wbf + 262144;
    ushort* wf1_bf  = wbf + 327680;
    ushort* wf2_bf  = wbf + 720896;
    (void)ws_size; (void)in_sizes; (void)n_in; (void)out_size;

    dim3 blk(256);

    // 0) weights -> bf16 ; biases concat ; 1) LN/transpose -> bf16
    k_wconv<<<dim3(416), blk, 0, stream>>>(Wq, Wqd, Wk, Wkd, Wv, Wf1, Wf2, wbf);
    k_bconcat<<<dim3(1), dim3(512), 0, stream>>>(bq, bqd, bk, bkd, bqqd, bkkd);
    k_ln_transpose<true ><<<dim3(B_ * (N_ / 64)), blk, 0, stream>>>(featA, ln_in_g, ln_in_b, fused_bf, 3 * C_);
    k_ln_transpose<false><<<dim3(B_ * (N_ / 64)), blk, 0, stream>>>(featB, nullptr, nullptr, featB_bf, C_);

    // 2) fused projections (R8 config): q|qd, k|kd, v^T
    k_gemm_bf<0,1><<<dim3(RN / 64, 8, 1), blk, 0, stream>>>(fused_bf, 3 * C_, 0, wqqd_bf, C_, 0, qqd_bf, 512, 0, C_, bqqd, nullptr);
    k_gemm_bf<0,1><<<dim3(RN / 64, 8, 1), blk, 0, stream>>>(featB_bf, C_,     0, wkkd_bf, C_, 0, kkd_bf, 512, 0, C_, bkkd, nullptr);
    k_gemm_bf<3,1><<<dim3(C_ / 64, N_ / 64, B_), blk, 0, stream>>>(wv_bf, C_, 0, featB_bf, C_, (size_t)N_ * C_, v_bf, N_, (size_t)C_ * N_, C_, bv, nullptr);

    // 3) feature-cdist (bf16 out, log2e-domain)
    k_rownorm<<<dim3(RN / 4), blk, 0, stream>>>(qd_bf, 512, qn);
    k_rownorm<<<dim3(RN / 4), blk, 0, stream>>>(kd_bf, 512, kn);
    k_gemm_bf<1,1><<<dim3(N_ / 64, N_ / 64, B_), blk, 0, stream>>>(qd_bf, 512, (size_t)N_ * 512,
                                                                   kd_bf, 512, (size_t)N_ * 512,
                                                                   cd_bf, N_, (size_t)N_ * N_, C_, qn, kn);

    // 4) fused attention v7 (single-barrier pipelined) + fused merge+LN
    k_attn7<<<dim3(N_ / 16, B_, 4), dim3(512), 0, stream>>>(q_bf, k_bf, v_bf, xyz_A, xyz_B, cd_bf,
                                                            sb_w1, sb_bn_g, sb_bn_b, sb_w2, sb_b2,
                                                            pc, pml);
    k_merge_ln<<<dim3(RN, 2), blk, 0, stream>>>(pc, pml, ln_sim_g, ln_sim_b, ln_dis_g, ln_dis_b, fused_bf);

    // 5) fused MLP: Wf1, Wf2 (64^2, R8 config)
    k_gemm_bf<2,1><<<dim3(RN / 64, 8, 1), blk, 0, stream>>>(fused_bf, 3 * C_, 0, wf1_bf, 3 * C_, 0, fh, 2 * C_, 0, 3 * C_, bnf_g, bnf_b);
    k_gemm_bf<0,0><<<dim3(RN / 64, 4, 1), blk, 0, stream>>>(fh, 2 * C_, 0, wf2_bf, 2 * C_, 0, fused_t, C_, 0, 2 * C_, bf2, nullptr);

    // 6) transpose + residual
    k_transpose_add<<<dim3(N_ / 64, C_ / 64, B_), blk, 0, stream>>>(fused_t, featA, out);
}